// Round 2
// baseline (1835.423 us; speedup 1.0000x reference)
//
#include <hip/hip_runtime.h>
#include <hip/hip_bf16.h>

#define N_NODES 100000
#define N_EDGES 1600000
#define IN_F 32
#define HID 128

// All float tensors are FP32 (per reference dtypes); edge_index is int32.

// ---------------- degree / normalization ----------------

__global__ void k_init_deg(float* __restrict__ deg) {
    int i = blockIdx.x * 256 + threadIdx.x;
    if (i < N_NODES) deg[i] = 1.0f;   // self-loop
}

__global__ void k_count(const int* __restrict__ dst, float* __restrict__ deg) {
    int e = blockIdx.x * 256 + threadIdx.x;
    if (e < N_EDGES) unsafeAtomicAdd(&deg[dst[e]], 1.0f);
}

__global__ void k_rsqrt(float* __restrict__ deg) {
    int i = blockIdx.x * 256 + threadIdx.x;
    if (i < N_NODES) deg[i] = rsqrtf(deg[i]);   // deg >= 1 always
}

// ---------------- layer 1 transform: x(f32,[N,32]) @ W1([32,128]) ----------------
// t[i] = (x[i] @ W) * dis[i]; written to both T and AGG (self-loop init).

__global__ __launch_bounds__(256) void k_xform1(
    const float* __restrict__ x, const float* __restrict__ W,
    const float* __restrict__ dis, float* __restrict__ T, float* __restrict__ AGG) {
    __shared__ float srow[2][IN_F];
    const int lr = threadIdx.x >> 7;      // local row 0..1
    const int j  = threadIdx.x & 127;     // output column
    float w[IN_F];
#pragma unroll
    for (int k = 0; k < IN_F; ++k) w[k] = W[k * HID + j];

    for (int base = blockIdx.x * 2; base < N_NODES; base += gridDim.x * 2) {
        if (threadIdx.x < 64) {
            int r = base + (threadIdx.x >> 5);
            int k = threadIdx.x & 31;
            srow[threadIdx.x >> 5][k] = (r < N_NODES) ? x[r * IN_F + k] : 0.0f;
        }
        __syncthreads();
        int row = base + lr;
        if (row < N_NODES) {
            const float* rp = srow[lr];
            float a0 = 0.f, a1 = 0.f, a2 = 0.f, a3 = 0.f;
#pragma unroll
            for (int k4 = 0; k4 < IN_F; k4 += 4) {
                float4 rv = *(const float4*)(rp + k4);
                a0 += rv.x * w[k4 + 0];
                a1 += rv.y * w[k4 + 1];
                a2 += rv.z * w[k4 + 2];
                a3 += rv.w * w[k4 + 3];
            }
            float acc = ((a0 + a1) + (a2 + a3)) * dis[row];
            T[row * HID + j]   = acc;
            AGG[row * HID + j] = acc;
        }
        __syncthreads();
    }
}

// ---------------- layer 2 transform: A(f32,[N,128]) @ W2([128,128]), in place ----------------

__global__ __launch_bounds__(256) void k_xform2(
    float* __restrict__ A, const float* __restrict__ W,
    const float* __restrict__ dis, float* __restrict__ AGG) {
    __shared__ float srow[2][HID];
    const int lr = threadIdx.x >> 7;
    const int j  = threadIdx.x & 127;
    float w[HID];
#pragma unroll
    for (int k = 0; k < HID; ++k) w[k] = W[k * HID + j];

    for (int base = blockIdx.x * 2; base < N_NODES; base += gridDim.x * 2) {
        {   // stage 2 rows: 256 threads load 256 floats
            int r = base + (threadIdx.x >> 7);
            int k = threadIdx.x & 127;
            srow[threadIdx.x >> 7][k] = (r < N_NODES) ? A[r * HID + k] : 0.f;
        }
        __syncthreads();
        int row = base + lr;
        if (row < N_NODES) {
            const float* rp = srow[lr];
            float a0 = 0.f, a1 = 0.f, a2 = 0.f, a3 = 0.f;
#pragma unroll
            for (int k4 = 0; k4 < HID; k4 += 4) {
                float4 rv = *(const float4*)(rp + k4);
                a0 += rv.x * w[k4 + 0];
                a1 += rv.y * w[k4 + 1];
                a2 += rv.z * w[k4 + 2];
                a3 += rv.w * w[k4 + 3];
            }
            float acc = ((a0 + a1) + (a2 + a3)) * dis[row];
            A[row * HID + j]   = acc;   // in place: this row fully staged above
            AGG[row * HID + j] = acc;
        }
        __syncthreads();
    }
}

// ---------------- layer 3 transform: A(f32,[N,128]) @ W3([128,32]) ----------------

__global__ __launch_bounds__(256) void k_xform3(
    const float* __restrict__ A, const float* __restrict__ W,
    const float* __restrict__ dis, float* __restrict__ T, float* __restrict__ AGG) {
    __shared__ float srow[8][HID];
    const int lr = threadIdx.x >> 5;     // 0..7
    const int j  = threadIdx.x & 31;
    float w[HID];
#pragma unroll
    for (int k = 0; k < HID; ++k) w[k] = W[k * IN_F + j];

    for (int base = blockIdx.x * 8; base < N_NODES; base += gridDim.x * 8) {
        for (int t = threadIdx.x; t < 8 * HID; t += 256) {
            int r = base + (t >> 7);
            srow[t >> 7][t & 127] = (r < N_NODES) ? A[r * HID + (t & 127)] : 0.f;
        }
        __syncthreads();
        int row = base + lr;
        if (row < N_NODES) {
            const float* rp = srow[lr];
            float a0 = 0.f, a1 = 0.f, a2 = 0.f, a3 = 0.f;
#pragma unroll
            for (int k4 = 0; k4 < HID; k4 += 4) {
                float4 rv = *(const float4*)(rp + k4);
                a0 += rv.x * w[k4 + 0];
                a1 += rv.y * w[k4 + 1];
                a2 += rv.z * w[k4 + 2];
                a3 += rv.w * w[k4 + 3];
            }
            float acc = ((a0 + a1) + (a2 + a3)) * dis[row];
            T[row * IN_F + j]   = acc;
            AGG[row * IN_F + j] = acc;
        }
        __syncthreads();
    }
}

// ---------------- edge scatter-add ----------------

__global__ void k_scatter128(const int* __restrict__ src, const int* __restrict__ dst,
                             const float* __restrict__ T, float* __restrict__ AGG) {
    const long long total  = (long long)N_EDGES * HID;
    const long long stride = (long long)gridDim.x * 256;
    for (long long tid = (long long)blockIdx.x * 256 + threadIdx.x; tid < total;
         tid += stride) {
        int e = (int)(tid >> 7);
        int j = (int)(tid & 127);
        float v = T[src[e] * HID + j];
        unsafeAtomicAdd(&AGG[dst[e] * HID + j], v);
    }
}

__global__ void k_scatter32(const int* __restrict__ src, const int* __restrict__ dst,
                            const float* __restrict__ T, float* __restrict__ AGG) {
    const long long total  = (long long)N_EDGES * IN_F;
    const long long stride = (long long)gridDim.x * 256;
    for (long long tid = (long long)blockIdx.x * 256 + threadIdx.x; tid < total;
         tid += stride) {
        int e = (int)(tid >> 5);
        int j = (int)(tid & 31);
        float v = T[src[e] * IN_F + j];
        unsafeAtomicAdd(&AGG[dst[e] * IN_F + j], v);
    }
}

// ---------------- epilogues: relu(agg*dis + b) ----------------

__global__ void k_epi128(const float* __restrict__ AGG, const float* __restrict__ dis,
                         const float* __restrict__ b, float* __restrict__ H) {
    int tid = blockIdx.x * 256 + threadIdx.x;   // exactly N*HID threads
    int i = tid >> 7, j = tid & 127;
    float v = AGG[tid] * dis[i] + b[j];
    H[tid] = v > 0.f ? v : 0.f;
}

__global__ void k_final(const float* __restrict__ AGG, const float* __restrict__ dis,
                        const float* __restrict__ b, float* __restrict__ out) {
    int tid = blockIdx.x * 256 + threadIdx.x;   // exactly N*IN_F threads
    int i = tid >> 5, j = tid & 31;
    float v = AGG[tid] * dis[i] + b[j];
    out[tid] = v > 0.f ? v : 0.f;
}

// ---------------- launch ----------------

extern "C" void kernel_launch(void* const* d_in, const int* in_sizes, int n_in,
                              void* d_out, int out_size, void* d_ws, size_t ws_size,
                              hipStream_t stream) {
    const float* x  = (const float*)d_in[0];
    const int*   ei = (const int*)d_in[1];
    const float* W1 = (const float*)d_in[2];
    const float* b1 = (const float*)d_in[3];
    const float* W2 = (const float*)d_in[4];
    const float* b2 = (const float*)d_in[5];
    const float* W3 = (const float*)d_in[6];
    const float* b3 = (const float*)d_in[7];
    float* out = (float*)d_out;

    const int* src = ei;             // edge_index[0]
    const int* dst = ei + N_EDGES;   // edge_index[1]

    float* deg = (float*)d_ws;                       // N (dis after rsqrt)
    float* A   = deg + 102400;                       // N*128 fp32
    float* B   = A + (size_t)N_NODES * HID;          // N*128 fp32
    float* T3   = B;                                 // N*32 view for layer 3
    float* AGG3 = B + (size_t)N_NODES * IN_F;        // N*32 view

    // normalization
    k_init_deg<<<(N_NODES + 255) / 256, 256, 0, stream>>>(deg);
    k_count<<<(N_EDGES + 255) / 256, 256, 0, stream>>>(dst, deg);
    k_rsqrt<<<(N_NODES + 255) / 256, 256, 0, stream>>>(deg);

    // layer 1: 32 -> 128
    k_xform1<<<2048, 256, 0, stream>>>(x, W1, deg, A, B);
    k_scatter128<<<102400, 256, 0, stream>>>(src, dst, A, B);
    k_epi128<<<(N_NODES * HID) / 256, 256, 0, stream>>>(B, deg, b1, A);

    // layer 2: 128 -> 128
    k_xform2<<<4096, 256, 0, stream>>>(A, W2, deg, B);
    k_scatter128<<<102400, 256, 0, stream>>>(src, dst, A, B);
    k_epi128<<<(N_NODES * HID) / 256, 256, 0, stream>>>(B, deg, b2, A);

    // layer 3: 128 -> 32
    k_xform3<<<2048, 256, 0, stream>>>(A, W3, deg, T3, AGG3);
    k_scatter32<<<25600, 256, 0, stream>>>(src, dst, T3, AGG3);
    k_final<<<(N_NODES * IN_F) / 256, 256, 0, stream>>>(AGG3, deg, b3, out);
}

// Round 3
// 813.244 us; speedup vs baseline: 2.2569x; 2.2569x over previous
//
#include <hip/hip_runtime.h>
#include <hip/hip_bf16.h>

#define N_NODES 100000
#define N_EDGES 1600000
#define IN_F 32
#define HID 128
#define NBLK_SCAN 391   // ceil(100000/256)

// ---------------- CSR build (counting sort by dst) ----------------

__global__ void k_zero_ideg(int* __restrict__ ideg) {
    int i = blockIdx.x * 256 + threadIdx.x;
    if (i < N_NODES) ideg[i] = 0;
}

__global__ void k_count(const int* __restrict__ dst, int* __restrict__ ideg) {
    int e = blockIdx.x * 256 + threadIdx.x;
    if (e < N_EDGES) atomicAdd(&ideg[dst[e]], 1);
}

// block-level exclusive scan; cursor <- exclusive prefix within block, partials[blk] <- block sum
__global__ __launch_bounds__(256) void k_scan1(const int* __restrict__ ideg,
                                               int* __restrict__ cursor,
                                               int* __restrict__ partials) {
    __shared__ int s[256];
    int gid = blockIdx.x * 256 + threadIdx.x;
    int v = (gid < N_NODES) ? ideg[gid] : 0;
    s[threadIdx.x] = v;
    __syncthreads();
    for (int off = 1; off < 256; off <<= 1) {
        int t = (threadIdx.x >= off) ? s[threadIdx.x - off] : 0;
        __syncthreads();
        s[threadIdx.x] += t;
        __syncthreads();
    }
    if (gid < N_NODES) cursor[gid] = s[threadIdx.x] - v;   // exclusive
    if (threadIdx.x == 255) partials[blockIdx.x] = s[255];
}

// single-block exclusive scan of the partials
__global__ __launch_bounds__(512) void k_scan2(int* __restrict__ partials) {
    __shared__ int s[512];
    int v = (threadIdx.x < NBLK_SCAN) ? partials[threadIdx.x] : 0;
    s[threadIdx.x] = v;
    __syncthreads();
    for (int off = 1; off < 512; off <<= 1) {
        int t = (threadIdx.x >= off) ? s[threadIdx.x - off] : 0;
        __syncthreads();
        s[threadIdx.x] += t;
        __syncthreads();
    }
    if (threadIdx.x < NBLK_SCAN) partials[threadIdx.x] = s[threadIdx.x] - v;
}

__global__ void k_scan3(int* __restrict__ cursor, const int* __restrict__ partials) {
    int gid = blockIdx.x * 256 + threadIdx.x;
    if (gid < N_NODES) cursor[gid] += partials[blockIdx.x];
}

// bump-allocator fill: after this, cursor[d] == row_end(d); row_start = cursor[d]-ideg[d]
__global__ void k_fill(const int* __restrict__ src, const int* __restrict__ dst,
                       int* __restrict__ cursor, int* __restrict__ col) {
    int e = blockIdx.x * 256 + threadIdx.x;
    if (e < N_EDGES) {
        int slot = atomicAdd(&cursor[dst[e]], 1);
        col[slot] = src[e];
    }
}

// ---------------- transforms: T[i] = (h[i] @ W) * dis[i] ----------------

__global__ __launch_bounds__(256) void k_xform1(
    const float* __restrict__ x, const float* __restrict__ W,
    const int* __restrict__ ideg, float* __restrict__ T) {
    __shared__ float srow[2][IN_F];
    const int lr = threadIdx.x >> 7;
    const int j  = threadIdx.x & 127;
    float w[IN_F];
#pragma unroll
    for (int k = 0; k < IN_F; ++k) w[k] = W[k * HID + j];

    for (int base = blockIdx.x * 2; base < N_NODES; base += gridDim.x * 2) {
        if (threadIdx.x < 64) {
            int r = base + (threadIdx.x >> 5);
            int k = threadIdx.x & 31;
            srow[threadIdx.x >> 5][k] = (r < N_NODES) ? x[r * IN_F + k] : 0.0f;
        }
        __syncthreads();
        int row = base + lr;
        if (row < N_NODES) {
            const float* rp = srow[lr];
            float a0 = 0.f, a1 = 0.f, a2 = 0.f, a3 = 0.f;
#pragma unroll
            for (int k4 = 0; k4 < IN_F; k4 += 4) {
                float4 rv = *(const float4*)(rp + k4);
                a0 += rv.x * w[k4 + 0];
                a1 += rv.y * w[k4 + 1];
                a2 += rv.z * w[k4 + 2];
                a3 += rv.w * w[k4 + 3];
            }
            float dis = rsqrtf(1.0f + (float)ideg[row]);
            T[row * HID + j] = ((a0 + a1) + (a2 + a3)) * dis;
        }
        __syncthreads();
    }
}

__global__ __launch_bounds__(256) void k_xform2(
    const float* __restrict__ H, const float* __restrict__ W,
    const int* __restrict__ ideg, float* __restrict__ T) {
    __shared__ float srow[2][HID];
    const int lr = threadIdx.x >> 7;
    const int j  = threadIdx.x & 127;
    float w[HID];
#pragma unroll
    for (int k = 0; k < HID; ++k) w[k] = W[k * HID + j];

    for (int base = blockIdx.x * 2; base < N_NODES; base += gridDim.x * 2) {
        {
            int r = base + (threadIdx.x >> 7);
            int k = threadIdx.x & 127;
            srow[threadIdx.x >> 7][k] = (r < N_NODES) ? H[r * HID + k] : 0.f;
        }
        __syncthreads();
        int row = base + lr;
        if (row < N_NODES) {
            const float* rp = srow[lr];
            float a0 = 0.f, a1 = 0.f, a2 = 0.f, a3 = 0.f;
#pragma unroll
            for (int k4 = 0; k4 < HID; k4 += 4) {
                float4 rv = *(const float4*)(rp + k4);
                a0 += rv.x * w[k4 + 0];
                a1 += rv.y * w[k4 + 1];
                a2 += rv.z * w[k4 + 2];
                a3 += rv.w * w[k4 + 3];
            }
            float dis = rsqrtf(1.0f + (float)ideg[row]);
            T[row * HID + j] = ((a0 + a1) + (a2 + a3)) * dis;
        }
        __syncthreads();
    }
}

__global__ __launch_bounds__(256) void k_xform3(
    const float* __restrict__ H, const float* __restrict__ W,
    const int* __restrict__ ideg, float* __restrict__ T) {
    __shared__ float srow[8][HID];
    const int lr = threadIdx.x >> 5;
    const int j  = threadIdx.x & 31;
    float w[HID];
#pragma unroll
    for (int k = 0; k < HID; ++k) w[k] = W[k * IN_F + j];

    for (int base = blockIdx.x * 8; base < N_NODES; base += gridDim.x * 8) {
        for (int t = threadIdx.x; t < 8 * HID; t += 256) {
            int r = base + (t >> 7);
            srow[t >> 7][t & 127] = (r < N_NODES) ? H[r * HID + (t & 127)] : 0.f;
        }
        __syncthreads();
        int row = base + lr;
        if (row < N_NODES) {
            const float* rp = srow[lr];
            float a0 = 0.f, a1 = 0.f, a2 = 0.f, a3 = 0.f;
#pragma unroll
            for (int k4 = 0; k4 < HID; k4 += 4) {
                float4 rv = *(const float4*)(rp + k4);
                a0 += rv.x * w[k4 + 0];
                a1 += rv.y * w[k4 + 1];
                a2 += rv.z * w[k4 + 2];
                a3 += rv.w * w[k4 + 3];
            }
            float dis = rsqrtf(1.0f + (float)ideg[row]);
            T[row * IN_F + j] = ((a0 + a1) + (a2 + a3)) * dis;
        }
        __syncthreads();
    }
}

// ---------------- fused gather + epilogue: out = relu((t_d + sum_nbr t_s)*dis_d + b) ----------------

__global__ __launch_bounds__(256) void k_gather128(
    const int* __restrict__ cursor, const int* __restrict__ ideg,
    const int* __restrict__ col, const float* __restrict__ T,
    const float* __restrict__ b, float* __restrict__ OUT) {
    int node = blockIdx.x * 2 + (threadIdx.x >> 7);
    int j = threadIdx.x & 127;
    if (node >= N_NODES) return;
    int end = cursor[node];
    int d   = ideg[node];
    int e   = end - d;
    float acc = T[(size_t)node * HID + j];   // self-loop
    for (; e + 3 < end; e += 4) {
        int s0 = col[e], s1 = col[e + 1], s2 = col[e + 2], s3 = col[e + 3];
        float v0 = T[(size_t)s0 * HID + j];
        float v1 = T[(size_t)s1 * HID + j];
        float v2 = T[(size_t)s2 * HID + j];
        float v3 = T[(size_t)s3 * HID + j];
        acc += (v0 + v1) + (v2 + v3);
    }
    for (; e < end; ++e) acc += T[(size_t)col[e] * HID + j];
    float dis = rsqrtf(1.0f + (float)d);
    float v = acc * dis + b[j];
    OUT[(size_t)node * HID + j] = v > 0.f ? v : 0.f;
}

__global__ __launch_bounds__(256) void k_gather32(
    const int* __restrict__ cursor, const int* __restrict__ ideg,
    const int* __restrict__ col, const float* __restrict__ T,
    const float* __restrict__ b, float* __restrict__ OUT) {
    int node = blockIdx.x * 8 + (threadIdx.x >> 5);
    int j = threadIdx.x & 31;
    if (node >= N_NODES) return;
    int end = cursor[node];
    int d   = ideg[node];
    int e   = end - d;
    float acc = T[(size_t)node * IN_F + j];   // self-loop
    for (; e + 3 < end; e += 4) {
        int s0 = col[e], s1 = col[e + 1], s2 = col[e + 2], s3 = col[e + 3];
        float v0 = T[(size_t)s0 * IN_F + j];
        float v1 = T[(size_t)s1 * IN_F + j];
        float v2 = T[(size_t)s2 * IN_F + j];
        float v3 = T[(size_t)s3 * IN_F + j];
        acc += (v0 + v1) + (v2 + v3);
    }
    for (; e < end; ++e) acc += T[(size_t)col[e] * IN_F + j];
    float dis = rsqrtf(1.0f + (float)d);
    float v = acc * dis + b[j];
    OUT[(size_t)node * IN_F + j] = v > 0.f ? v : 0.f;
}

// ---------------- launch ----------------

extern "C" void kernel_launch(void* const* d_in, const int* in_sizes, int n_in,
                              void* d_out, int out_size, void* d_ws, size_t ws_size,
                              hipStream_t stream) {
    const float* x  = (const float*)d_in[0];
    const int*   ei = (const int*)d_in[1];
    const float* W1 = (const float*)d_in[2];
    const float* b1 = (const float*)d_in[3];
    const float* W2 = (const float*)d_in[4];
    const float* b2 = (const float*)d_in[5];
    const float* W3 = (const float*)d_in[6];
    const float* b3 = (const float*)d_in[7];
    float* out = (float*)d_out;

    const int* src = ei;             // edge_index[0]
    const int* dst = ei + N_EDGES;   // edge_index[1]

    // workspace layout
    int*   ideg     = (int*)d_ws;                    // N
    int*   cursor   = ideg + 102400;                 // N
    int*   partials = cursor + 102400;               // 512
    int*   col      = partials + 512;                // E
    float* A        = (float*)(col + N_EDGES);       // N*128  (T buffer)
    float* B        = A + (size_t)N_NODES * HID;     // N*128  (H buffer)

    // ---- CSR build (once, reused by all 3 layers) ----
    k_zero_ideg<<<NBLK_SCAN, 256, 0, stream>>>(ideg);
    k_count<<<(N_EDGES + 255) / 256, 256, 0, stream>>>(dst, ideg);
    k_scan1<<<NBLK_SCAN, 256, 0, stream>>>(ideg, cursor, partials);
    k_scan2<<<1, 512, 0, stream>>>(partials);
    k_scan3<<<NBLK_SCAN, 256, 0, stream>>>(cursor, partials);
    k_fill<<<(N_EDGES + 255) / 256, 256, 0, stream>>>(src, dst, cursor, col);

    // ---- layer 1: 32 -> 128 ----
    k_xform1<<<2048, 256, 0, stream>>>(x, W1, ideg, A);
    k_gather128<<<N_NODES / 2, 256, 0, stream>>>(cursor, ideg, col, A, b1, B);

    // ---- layer 2: 128 -> 128 ----
    k_xform2<<<4096, 256, 0, stream>>>(B, W2, ideg, A);
    k_gather128<<<N_NODES / 2, 256, 0, stream>>>(cursor, ideg, col, A, b2, B);

    // ---- layer 3: 128 -> 32 ----
    k_xform3<<<2048, 256, 0, stream>>>(B, W3, ideg, A);
    k_gather32<<<N_NODES / 8, 256, 0, stream>>>(cursor, ideg, col, A, b3, out);
}

// Round 4
// 632.393 us; speedup vs baseline: 2.9023x; 1.2860x over previous
//
#include <hip/hip_runtime.h>
#include <hip/hip_fp16.h>

#define N_NODES 100000
#define N_EDGES 1600000
#define IN_F 32
#define HID 128
#define NBLK_SCAN 391   // ceil(100000/256)

// ---------------- CSR build (counting sort by dst) ----------------

__global__ void k_zero_ideg(int* __restrict__ ideg) {
    int i = blockIdx.x * 256 + threadIdx.x;
    if (i < N_NODES) ideg[i] = 0;
}

__global__ void k_count(const int* __restrict__ dst, int* __restrict__ ideg) {
    int e = blockIdx.x * 256 + threadIdx.x;
    if (e < N_EDGES) atomicAdd(&ideg[dst[e]], 1);
}

__global__ __launch_bounds__(256) void k_scan1(const int* __restrict__ ideg,
                                               int* __restrict__ cursor,
                                               int* __restrict__ partials) {
    __shared__ int s[256];
    int gid = blockIdx.x * 256 + threadIdx.x;
    int v = (gid < N_NODES) ? ideg[gid] : 0;
    s[threadIdx.x] = v;
    __syncthreads();
    for (int off = 1; off < 256; off <<= 1) {
        int t = (threadIdx.x >= off) ? s[threadIdx.x - off] : 0;
        __syncthreads();
        s[threadIdx.x] += t;
        __syncthreads();
    }
    if (gid < N_NODES) cursor[gid] = s[threadIdx.x] - v;   // exclusive
    if (threadIdx.x == 255) partials[blockIdx.x] = s[255];
}

__global__ __launch_bounds__(512) void k_scan2(int* __restrict__ partials) {
    __shared__ int s[512];
    int v = (threadIdx.x < NBLK_SCAN) ? partials[threadIdx.x] : 0;
    s[threadIdx.x] = v;
    __syncthreads();
    for (int off = 1; off < 512; off <<= 1) {
        int t = (threadIdx.x >= off) ? s[threadIdx.x - off] : 0;
        __syncthreads();
        s[threadIdx.x] += t;
        __syncthreads();
    }
    if (threadIdx.x < NBLK_SCAN) partials[threadIdx.x] = s[threadIdx.x] - v;
}

__global__ void k_scan3(int* __restrict__ cursor, const int* __restrict__ partials) {
    int gid = blockIdx.x * 256 + threadIdx.x;
    if (gid < N_NODES) cursor[gid] += partials[blockIdx.x];
}

// bump fill: after this cursor[d] == row_end(d); row_start = cursor[d]-ideg[d]
__global__ void k_fill(const int* __restrict__ src, const int* __restrict__ dst,
                       int* __restrict__ cursor, int* __restrict__ col) {
    int e = blockIdx.x * 256 + threadIdx.x;
    if (e < N_EDGES) {
        int slot = atomicAdd(&cursor[dst[e]], 1);
        col[slot] = src[e];
    }
}

// ---------------- layer-1 prescale: t1 = x * dis (fp16, 32-dim) ----------------

__global__ void k_prescale(const float2* __restrict__ x, const int* __restrict__ ideg,
                           __half2* __restrict__ T) {
    int tid = blockIdx.x * 256 + threadIdx.x;   // N*16 half2 elements
    if (tid >= N_NODES * 16) return;
    int i = tid >> 4;
    float dis = rsqrtf(1.0f + (float)ideg[i]);
    float2 v = x[tid];
    T[tid] = __floats2half2_rn(v.x * dis, v.y * dis);
}

// ---------------- gathers (CSR, fp16 messages, half2 lanes) ----------------
// 32-dim: 16 half2/node, 16 nodes per 256-block.
// BIAS_RELU=false: OUT = acc*dis               (layer-1: feeds transform)
// BIAS_RELU=true : OUT = relu(acc*dis + b)     (layer-3: final)

template <bool BIAS_RELU>
__global__ __launch_bounds__(256) void k_gather32h(
    const int* __restrict__ cursor, const int* __restrict__ ideg,
    const int* __restrict__ col, const __half2* __restrict__ T,
    const float* __restrict__ b, float2* __restrict__ OUT) {
    int node = blockIdx.x * 16 + (threadIdx.x >> 4);
    int j = threadIdx.x & 15;
    if (node >= N_NODES) return;
    int end = cursor[node];
    int d   = ideg[node];
    int e   = end - d;
    float2 acc = __half22float2(T[(size_t)node * 16 + j]);   // self-loop
    for (; e + 3 < end; e += 4) {
        int s0 = col[e], s1 = col[e + 1], s2 = col[e + 2], s3 = col[e + 3];
        float2 f0 = __half22float2(T[(size_t)s0 * 16 + j]);
        float2 f1 = __half22float2(T[(size_t)s1 * 16 + j]);
        float2 f2 = __half22float2(T[(size_t)s2 * 16 + j]);
        float2 f3 = __half22float2(T[(size_t)s3 * 16 + j]);
        acc.x += (f0.x + f1.x) + (f2.x + f3.x);
        acc.y += (f0.y + f1.y) + (f2.y + f3.y);
    }
    for (; e < end; ++e) {
        float2 f = __half22float2(T[(size_t)col[e] * 16 + j]);
        acc.x += f.x; acc.y += f.y;
    }
    float dis = rsqrtf(1.0f + (float)d);
    float vx = acc.x * dis, vy = acc.y * dis;
    if constexpr (BIAS_RELU) {
        vx += b[2 * j];     vy += b[2 * j + 1];
        vx = vx > 0.f ? vx : 0.f;
        vy = vy > 0.f ? vy : 0.f;
    }
    OUT[(size_t)node * 16 + j] = make_float2(vx, vy);
}

// 128-dim: 64 half2/node, 4 nodes per 256-block. OUT = relu(acc*dis + b).
__global__ __launch_bounds__(256) void k_gather128h(
    const int* __restrict__ cursor, const int* __restrict__ ideg,
    const int* __restrict__ col, const __half2* __restrict__ T,
    const float* __restrict__ b, float2* __restrict__ OUT) {
    int node = blockIdx.x * 4 + (threadIdx.x >> 6);
    int j = threadIdx.x & 63;
    if (node >= N_NODES) return;
    int end = cursor[node];
    int d   = ideg[node];
    int e   = end - d;
    float2 acc = __half22float2(T[(size_t)node * 64 + j]);   // self-loop
    for (; e + 3 < end; e += 4) {
        int s0 = col[e], s1 = col[e + 1], s2 = col[e + 2], s3 = col[e + 3];
        float2 f0 = __half22float2(T[(size_t)s0 * 64 + j]);
        float2 f1 = __half22float2(T[(size_t)s1 * 64 + j]);
        float2 f2 = __half22float2(T[(size_t)s2 * 64 + j]);
        float2 f3 = __half22float2(T[(size_t)s3 * 64 + j]);
        acc.x += (f0.x + f1.x) + (f2.x + f3.x);
        acc.y += (f0.y + f1.y) + (f2.y + f3.y);
    }
    for (; e < end; ++e) {
        float2 f = __half22float2(T[(size_t)col[e] * 64 + j]);
        acc.x += f.x; acc.y += f.y;
    }
    float dis = rsqrtf(1.0f + (float)d);
    float vx = acc.x * dis + b[2 * j];
    float vy = acc.y * dis + b[2 * j + 1];
    OUT[(size_t)node * 64 + j] =
        make_float2(vx > 0.f ? vx : 0.f, vy > 0.f ? vy : 0.f);
}

// ---------------- transforms ----------------

// layer 1 (after aggregate): H = relu(z @ W1 + b1), z fp32 [N,32], H fp32 [N,128]
__global__ __launch_bounds__(256) void k_xform1(
    const float* __restrict__ z, const float* __restrict__ W,
    const float* __restrict__ b, float* __restrict__ H) {
    __shared__ float srow[2][IN_F];
    const int lr = threadIdx.x >> 7;
    const int j  = threadIdx.x & 127;
    float w[IN_F];
#pragma unroll
    for (int k = 0; k < IN_F; ++k) w[k] = W[k * HID + j];
    const float bj = b[j];

    for (int base = blockIdx.x * 2; base < N_NODES; base += gridDim.x * 2) {
        if (threadIdx.x < 64) {
            int r = base + (threadIdx.x >> 5);
            int k = threadIdx.x & 31;
            srow[threadIdx.x >> 5][k] = (r < N_NODES) ? z[r * IN_F + k] : 0.0f;
        }
        __syncthreads();
        int row = base + lr;
        if (row < N_NODES) {
            const float* rp = srow[lr];
            float a0 = 0.f, a1 = 0.f, a2 = 0.f, a3 = 0.f;
#pragma unroll
            for (int k4 = 0; k4 < IN_F; k4 += 4) {
                float4 rv = *(const float4*)(rp + k4);
                a0 += rv.x * w[k4 + 0];
                a1 += rv.y * w[k4 + 1];
                a2 += rv.z * w[k4 + 2];
                a3 += rv.w * w[k4 + 3];
            }
            float v = ((a0 + a1) + (a2 + a3)) + bj;
            H[row * HID + j] = v > 0.f ? v : 0.f;
        }
        __syncthreads();
    }
}

// layer 2: T = (H @ W2) * dis, fp16 out [N,128]
__global__ __launch_bounds__(256) void k_xform2(
    const float* __restrict__ H, const float* __restrict__ W,
    const int* __restrict__ ideg, __half* __restrict__ T) {
    __shared__ float srow[2][HID];
    const int lr = threadIdx.x >> 7;
    const int j  = threadIdx.x & 127;
    float w[HID];
#pragma unroll
    for (int k = 0; k < HID; ++k) w[k] = W[k * HID + j];

    for (int base = blockIdx.x * 2; base < N_NODES; base += gridDim.x * 2) {
        {
            int r = base + (threadIdx.x >> 7);
            int k = threadIdx.x & 127;
            srow[threadIdx.x >> 7][k] = (r < N_NODES) ? H[r * HID + k] : 0.f;
        }
        __syncthreads();
        int row = base + lr;
        if (row < N_NODES) {
            const float* rp = srow[lr];
            float a0 = 0.f, a1 = 0.f, a2 = 0.f, a3 = 0.f;
#pragma unroll
            for (int k4 = 0; k4 < HID; k4 += 4) {
                float4 rv = *(const float4*)(rp + k4);
                a0 += rv.x * w[k4 + 0];
                a1 += rv.y * w[k4 + 1];
                a2 += rv.z * w[k4 + 2];
                a3 += rv.w * w[k4 + 3];
            }
            float dis = rsqrtf(1.0f + (float)ideg[row]);
            T[row * HID + j] = __float2half_rn(((a0 + a1) + (a2 + a3)) * dis);
        }
        __syncthreads();
    }
}

// layer 3: T = (H @ W3) * dis, fp16 out [N,32]
__global__ __launch_bounds__(256) void k_xform3(
    const float* __restrict__ H, const float* __restrict__ W,
    const int* __restrict__ ideg, __half* __restrict__ T) {
    __shared__ float srow[8][HID];
    const int lr = threadIdx.x >> 5;
    const int j  = threadIdx.x & 31;
    float w[HID];
#pragma unroll
    for (int k = 0; k < HID; ++k) w[k] = W[k * IN_F + j];

    for (int base = blockIdx.x * 8; base < N_NODES; base += gridDim.x * 8) {
        for (int t = threadIdx.x; t < 8 * HID; t += 256) {
            int r = base + (t >> 7);
            srow[t >> 7][t & 127] = (r < N_NODES) ? H[r * HID + (t & 127)] : 0.f;
        }
        __syncthreads();
        int row = base + lr;
        if (row < N_NODES) {
            const float* rp = srow[lr];
            float a0 = 0.f, a1 = 0.f, a2 = 0.f, a3 = 0.f;
#pragma unroll
            for (int k4 = 0; k4 < HID; k4 += 4) {
                float4 rv = *(const float4*)(rp + k4);
                a0 += rv.x * w[k4 + 0];
                a1 += rv.y * w[k4 + 1];
                a2 += rv.z * w[k4 + 2];
                a3 += rv.w * w[k4 + 3];
            }
            float dis = rsqrtf(1.0f + (float)ideg[row]);
            T[row * IN_F + j] = __float2half_rn(((a0 + a1) + (a2 + a3)) * dis);
        }
        __syncthreads();
    }
}

// ---------------- launch ----------------

extern "C" void kernel_launch(void* const* d_in, const int* in_sizes, int n_in,
                              void* d_out, int out_size, void* d_ws, size_t ws_size,
                              hipStream_t stream) {
    const float* x  = (const float*)d_in[0];
    const int*   ei = (const int*)d_in[1];
    const float* W1 = (const float*)d_in[2];
    const float* b1 = (const float*)d_in[3];
    const float* W2 = (const float*)d_in[4];
    const float* b2 = (const float*)d_in[5];
    const float* W3 = (const float*)d_in[6];
    const float* b3 = (const float*)d_in[7];
    float* out = (float*)d_out;

    const int* src = ei;             // edge_index[0]
    const int* dst = ei + N_EDGES;   // edge_index[1]

    // workspace layout
    int*     ideg     = (int*)d_ws;                        // N (padded 102400)
    int*     cursor   = ideg + 102400;                     // N
    int*     partials = cursor + 102400;                   // 512
    int*     col      = partials + 512;                    // E
    __half2* t1h      = (__half2*)(col + N_EDGES);         // N*16 half2 (32-dim msgs)
    float*   z        = (float*)(t1h + (size_t)N_NODES * 16);   // N*32 fp32
    float*   H        = z + (size_t)N_NODES * IN_F;        // N*128 fp32
    __half*  T2h      = (__half*)(H + (size_t)N_NODES * HID);   // N*128 half (reused as N*32 for L3)

    // ---- CSR build ----
    k_zero_ideg<<<NBLK_SCAN, 256, 0, stream>>>(ideg);
    k_count<<<(N_EDGES + 255) / 256, 256, 0, stream>>>(dst, ideg);
    k_scan1<<<NBLK_SCAN, 256, 0, stream>>>(ideg, cursor, partials);
    k_scan2<<<1, 512, 0, stream>>>(partials);
    k_scan3<<<NBLK_SCAN, 256, 0, stream>>>(cursor, partials);
    k_fill<<<(N_EDGES + 255) / 256, 256, 0, stream>>>(src, dst, cursor, col);

    // ---- layer 1 (aggregate-first; 32-dim gather) ----
    k_prescale<<<(N_NODES * 16 + 255) / 256, 256, 0, stream>>>(
        (const float2*)x, ideg, t1h);
    k_gather32h<false><<<(N_NODES + 15) / 16, 256, 0, stream>>>(
        cursor, ideg, col, t1h, nullptr, (float2*)z);
    k_xform1<<<2048, 256, 0, stream>>>(z, W1, b1, H);

    // ---- layer 2 (transform-first; 128-dim fp16 gather) ----
    k_xform2<<<4096, 256, 0, stream>>>(H, W2, ideg, T2h);
    k_gather128h<<<(N_NODES + 3) / 4, 256, 0, stream>>>(
        cursor, ideg, col, (const __half2*)T2h, b2, (float2*)H);

    // ---- layer 3 (transform-first; 32-dim fp16 gather) ----
    k_xform3<<<2048, 256, 0, stream>>>(H, W3, ideg, T2h);
    k_gather32h<true><<<(N_NODES + 15) / 16, 256, 0, stream>>>(
        cursor, ideg, col, (const __half2*)T2h, b3, (float2*)out);
}

// Round 5
// 454.346 us; speedup vs baseline: 4.0397x; 1.3919x over previous
//
#include <hip/hip_runtime.h>
#include <hip/hip_fp16.h>

#define N_NODES 100000
#define N_EDGES 1600000
#define IN_F 32
#define HID 128
#define NBLK_SCAN 391   // ceil(100000/256)

typedef _Float16 half8 __attribute__((ext_vector_type(8)));
typedef float floatx4 __attribute__((ext_vector_type(4)));

static __device__ __forceinline__ void pack2(_Float16* dst, float a, float b) {
    union { _Float16 h[2]; unsigned u; } p;
    p.h[0] = (_Float16)a; p.h[1] = (_Float16)b;
    *(unsigned*)dst = p.u;
}

// ---------------- CSR build (counting sort by dst) ----------------

__global__ void k_zero_ideg(int* __restrict__ ideg) {
    int i = blockIdx.x * 256 + threadIdx.x;
    if (i < N_NODES) ideg[i] = 0;
}

__global__ void k_count(const int* __restrict__ dst, int* __restrict__ ideg) {
    int e = blockIdx.x * 256 + threadIdx.x;
    if (e < N_EDGES) atomicAdd(&ideg[dst[e]], 1);
}

__global__ __launch_bounds__(256) void k_scan1(const int* __restrict__ ideg,
                                               int* __restrict__ cursor,
                                               int* __restrict__ partials) {
    __shared__ int s[256];
    int gid = blockIdx.x * 256 + threadIdx.x;
    int v = (gid < N_NODES) ? ideg[gid] : 0;
    s[threadIdx.x] = v;
    __syncthreads();
    for (int off = 1; off < 256; off <<= 1) {
        int t = (threadIdx.x >= off) ? s[threadIdx.x - off] : 0;
        __syncthreads();
        s[threadIdx.x] += t;
        __syncthreads();
    }
    if (gid < N_NODES) cursor[gid] = s[threadIdx.x] - v;   // exclusive
    if (threadIdx.x == 255) partials[blockIdx.x] = s[255];
}

__global__ __launch_bounds__(512) void k_scan2(int* __restrict__ partials) {
    __shared__ int s[512];
    int v = (threadIdx.x < NBLK_SCAN) ? partials[threadIdx.x] : 0;
    s[threadIdx.x] = v;
    __syncthreads();
    for (int off = 1; off < 512; off <<= 1) {
        int t = (threadIdx.x >= off) ? s[threadIdx.x - off] : 0;
        __syncthreads();
        s[threadIdx.x] += t;
        __syncthreads();
    }
    if (threadIdx.x < NBLK_SCAN) partials[threadIdx.x] = s[threadIdx.x] - v;
}

__global__ void k_scan3(int* __restrict__ cursor, const int* __restrict__ partials) {
    int gid = blockIdx.x * 256 + threadIdx.x;
    if (gid < N_NODES) cursor[gid] += partials[blockIdx.x];
}

__global__ void k_fill(const int* __restrict__ src, const int* __restrict__ dst,
                       int* __restrict__ cursor, int* __restrict__ col) {
    int e = blockIdx.x * 256 + threadIdx.x;
    if (e < N_EDGES) {
        int slot = atomicAdd(&cursor[dst[e]], 1);
        col[slot] = src[e];
    }
}

// ---------------- layer-1 prescale: t1 = x * dis (fp16, 32-dim) ----------------

__global__ void k_prescale(const float2* __restrict__ x, const int* __restrict__ ideg,
                           __half2* __restrict__ T) {
    int tid = blockIdx.x * 256 + threadIdx.x;   // N*16 half2 elements
    if (tid >= N_NODES * 16) return;
    int i = tid >> 4;
    float dis = rsqrtf(1.0f + (float)ideg[i]);
    float2 v = x[tid];
    T[tid] = __floats2half2_rn(v.x * dis, v.y * dis);
}

// ---------------- gathers (CSR, fp16 messages, half2 lanes) ----------------

// 32-dim, fp32 out (feeds xform1): OUT = acc*dis
__global__ __launch_bounds__(256) void k_gather32h_pre(
    const int* __restrict__ cursor, const int* __restrict__ ideg,
    const int* __restrict__ col, const __half2* __restrict__ T,
    float2* __restrict__ OUT) {
    int node = blockIdx.x * 16 + (threadIdx.x >> 4);
    int j = threadIdx.x & 15;
    if (node >= N_NODES) return;
    int end = cursor[node];
    int d   = ideg[node];
    int e   = end - d;
    float2 acc = __half22float2(T[(size_t)node * 16 + j]);   // self-loop
    for (; e + 3 < end; e += 4) {
        int s0 = col[e], s1 = col[e + 1], s2 = col[e + 2], s3 = col[e + 3];
        float2 f0 = __half22float2(T[(size_t)s0 * 16 + j]);
        float2 f1 = __half22float2(T[(size_t)s1 * 16 + j]);
        float2 f2 = __half22float2(T[(size_t)s2 * 16 + j]);
        float2 f3 = __half22float2(T[(size_t)s3 * 16 + j]);
        acc.x += (f0.x + f1.x) + (f2.x + f3.x);
        acc.y += (f0.y + f1.y) + (f2.y + f3.y);
    }
    for (; e < end; ++e) {
        float2 f = __half22float2(T[(size_t)col[e] * 16 + j]);
        acc.x += f.x; acc.y += f.y;
    }
    float dis = rsqrtf(1.0f + (float)d);
    OUT[(size_t)node * 16 + j] = make_float2(acc.x * dis, acc.y * dis);
}

// 32-dim, final: out = relu(acc*dis + b), fp32
__global__ __launch_bounds__(256) void k_gather32h_fin(
    const int* __restrict__ cursor, const int* __restrict__ ideg,
    const int* __restrict__ col, const __half2* __restrict__ T,
    const float* __restrict__ b, float2* __restrict__ OUT) {
    int node = blockIdx.x * 16 + (threadIdx.x >> 4);
    int j = threadIdx.x & 15;
    if (node >= N_NODES) return;
    int end = cursor[node];
    int d   = ideg[node];
    int e   = end - d;
    float2 acc = __half22float2(T[(size_t)node * 16 + j]);   // self-loop
    for (; e + 3 < end; e += 4) {
        int s0 = col[e], s1 = col[e + 1], s2 = col[e + 2], s3 = col[e + 3];
        float2 f0 = __half22float2(T[(size_t)s0 * 16 + j]);
        float2 f1 = __half22float2(T[(size_t)s1 * 16 + j]);
        float2 f2 = __half22float2(T[(size_t)s2 * 16 + j]);
        float2 f3 = __half22float2(T[(size_t)s3 * 16 + j]);
        acc.x += (f0.x + f1.x) + (f2.x + f3.x);
        acc.y += (f0.y + f1.y) + (f2.y + f3.y);
    }
    for (; e < end; ++e) {
        float2 f = __half22float2(T[(size_t)col[e] * 16 + j]);
        acc.x += f.x; acc.y += f.y;
    }
    float dis = rsqrtf(1.0f + (float)d);
    float vx = acc.x * dis + b[2 * j];
    float vy = acc.y * dis + b[2 * j + 1];
    OUT[(size_t)node * 16 + j] =
        make_float2(vx > 0.f ? vx : 0.f, vy > 0.f ? vy : 0.f);
}

// 128-dim: H2 = relu(acc*dis + b), fp16 out (feeds xform3's MFMA A)
__global__ __launch_bounds__(256) void k_gather128h(
    const int* __restrict__ cursor, const int* __restrict__ ideg,
    const int* __restrict__ col, const __half2* __restrict__ T,
    const float* __restrict__ b, __half2* __restrict__ OUT) {
    int node = blockIdx.x * 4 + (threadIdx.x >> 6);
    int j = threadIdx.x & 63;
    if (node >= N_NODES) return;
    int end = cursor[node];
    int d   = ideg[node];
    int e   = end - d;
    float2 acc = __half22float2(T[(size_t)node * 64 + j]);   // self-loop
    for (; e + 3 < end; e += 4) {
        int s0 = col[e], s1 = col[e + 1], s2 = col[e + 2], s3 = col[e + 3];
        float2 f0 = __half22float2(T[(size_t)s0 * 64 + j]);
        float2 f1 = __half22float2(T[(size_t)s1 * 64 + j]);
        float2 f2 = __half22float2(T[(size_t)s2 * 64 + j]);
        float2 f3 = __half22float2(T[(size_t)s3 * 64 + j]);
        acc.x += (f0.x + f1.x) + (f2.x + f3.x);
        acc.y += (f0.y + f1.y) + (f2.y + f3.y);
    }
    for (; e < end; ++e) {
        float2 f = __half22float2(T[(size_t)col[e] * 64 + j]);
        acc.x += f.x; acc.y += f.y;
    }
    float dis = rsqrtf(1.0f + (float)d);
    float vx = acc.x * dis + b[2 * j];
    float vy = acc.y * dis + b[2 * j + 1];
    OUT[(size_t)node * 64 + j] =
        __floats2half2_rn(vx > 0.f ? vx : 0.f, vy > 0.f ? vy : 0.f);
}

// ---------------- MFMA transforms ----------------
// Fragment layouts (16x16x32): A[m=lane&15][k=quad*8+j], B[k=quad*8+j][n=lane&15],
// D[row=quad*4+r][col=lane&15]. Block = 4 waves x 16 rows = 64 rows.

// layer 1: H1 = relu(z @ W1 + b1); z fp32 [N,32], W1 fp32 [32,128], H1 fp16 [N,128]
__global__ __launch_bounds__(256) void k_xform1_mfma(
    const float* __restrict__ z, const float* __restrict__ W,
    const float* __restrict__ bias, _Float16* __restrict__ Hh) {
    __shared__ _Float16 Wt[128 * 40];   // Wt[n][k], stride 40 halves (80 B, 16B-aligned)
    for (int idx = threadIdx.x; idx < 2048; idx += 256) {
        int n = idx & 127, k = (idx >> 7) * 2;
        pack2(&Wt[n * 40 + k], W[k * HID + n], W[(k + 1) * HID + n]);
    }
    __syncthreads();

    const int lane = threadIdx.x & 63;
    const int wave = threadIdx.x >> 6;
    const int m16 = lane & 15, quad = lane >> 4;
    const int row0 = blockIdx.x * 64 + wave * 16;
    if (row0 >= N_NODES) return;

    int arow = row0 + m16; if (arow >= N_NODES) arow = N_NODES - 1;
    const float* zp = z + (size_t)arow * IN_F + quad * 8;
    float4 z0 = *(const float4*)zp;
    float4 z1 = *(const float4*)(zp + 4);
    half8 a = {(_Float16)z0.x, (_Float16)z0.y, (_Float16)z0.z, (_Float16)z0.w,
               (_Float16)z1.x, (_Float16)z1.y, (_Float16)z1.z, (_Float16)z1.w};

    floatx4 acc[8];
#pragma unroll
    for (int t = 0; t < 8; ++t) acc[t] = (floatx4){0.f, 0.f, 0.f, 0.f};
#pragma unroll
    for (int t = 0; t < 8; ++t) {
        half8 b = *(const half8*)&Wt[(t * 16 + m16) * 40 + quad * 8];
        acc[t] = __builtin_amdgcn_mfma_f32_16x16x32_f16(a, b, acc[t], 0, 0, 0);
    }
#pragma unroll
    for (int t = 0; t < 8; ++t) {
        int c = t * 16 + m16;
        float bj = bias[c];
#pragma unroll
        for (int r = 0; r < 4; ++r) {
            int row = row0 + quad * 4 + r;
            if (row < N_NODES) {
                float v = acc[t][r] + bj;
                Hh[(size_t)row * HID + c] = (_Float16)(v > 0.f ? v : 0.f);
            }
        }
    }
}

// layer 2: T2 = (H1 @ W2) * dis; H1 fp16 [N,128], W2 fp32 [128,128], T2 fp16 [N,128]
__global__ __launch_bounds__(256) void k_xform2_mfma(
    const _Float16* __restrict__ H, const float* __restrict__ W,
    const int* __restrict__ ideg, _Float16* __restrict__ T) {
    __shared__ _Float16 Wt[128 * 136];   // Wt[n][k], stride 136 halves (272 B, 16B-aligned)
    for (int idx = threadIdx.x; idx < 8192; idx += 256) {
        int n = idx & 127, k = (idx >> 7) * 2;
        pack2(&Wt[n * 136 + k], W[k * HID + n], W[(k + 1) * HID + n]);
    }
    __syncthreads();

    const int lane = threadIdx.x & 63;
    const int wave = threadIdx.x >> 6;
    const int m16 = lane & 15, quad = lane >> 4;
    const int row0 = blockIdx.x * 64 + wave * 16;
    if (row0 >= N_NODES) return;

    int arow = row0 + m16; if (arow >= N_NODES) arow = N_NODES - 1;
    const _Float16* hp = H + (size_t)arow * HID + quad * 8;
    half8 a[4];
#pragma unroll
    for (int kk = 0; kk < 4; ++kk) a[kk] = *(const half8*)(hp + kk * 32);

    floatx4 acc[8];
#pragma unroll
    for (int t = 0; t < 8; ++t) acc[t] = (floatx4){0.f, 0.f, 0.f, 0.f};
#pragma unroll
    for (int t = 0; t < 8; ++t) {
        const _Float16* wp = &Wt[(t * 16 + m16) * 136 + quad * 8];
#pragma unroll
        for (int kk = 0; kk < 4; ++kk) {
            half8 b = *(const half8*)(wp + kk * 32);
            acc[t] = __builtin_amdgcn_mfma_f32_16x16x32_f16(a[kk], b, acc[t], 0, 0, 0);
        }
    }
    float dis[4];
#pragma unroll
    for (int r = 0; r < 4; ++r) {
        int row = row0 + quad * 4 + r;
        dis[r] = (row < N_NODES) ? rsqrtf(1.0f + (float)ideg[row]) : 0.f;
    }
#pragma unroll
    for (int t = 0; t < 8; ++t) {
        int c = t * 16 + m16;
#pragma unroll
        for (int r = 0; r < 4; ++r) {
            int row = row0 + quad * 4 + r;
            if (row < N_NODES)
                T[(size_t)row * HID + c] = (_Float16)(acc[t][r] * dis[r]);
        }
    }
}

// layer 3: T3 = (H2 @ W3) * dis; H2 fp16 [N,128], W3 fp32 [128,32], T3 fp16 [N,32]
__global__ __launch_bounds__(256) void k_xform3_mfma(
    const _Float16* __restrict__ H, const float* __restrict__ W,
    const int* __restrict__ ideg, _Float16* __restrict__ T) {
    __shared__ _Float16 Wt[32 * 136];
    for (int idx = threadIdx.x; idx < 2048; idx += 256) {
        int n = idx & 31, k = (idx >> 5) * 2;
        pack2(&Wt[n * 136 + k], W[k * IN_F + n], W[(k + 1) * IN_F + n]);
    }
    __syncthreads();

    const int lane = threadIdx.x & 63;
    const int wave = threadIdx.x >> 6;
    const int m16 = lane & 15, quad = lane >> 4;
    const int row0 = blockIdx.x * 64 + wave * 16;
    if (row0 >= N_NODES) return;

    int arow = row0 + m16; if (arow >= N_NODES) arow = N_NODES - 1;
    const _Float16* hp = H + (size_t)arow * HID + quad * 8;
    half8 a[4];
#pragma unroll
    for (int kk = 0; kk < 4; ++kk) a[kk] = *(const half8*)(hp + kk * 32);

    floatx4 acc[2];
#pragma unroll
    for (int t = 0; t < 2; ++t) acc[t] = (floatx4){0.f, 0.f, 0.f, 0.f};
#pragma unroll
    for (int t = 0; t < 2; ++t) {
        const _Float16* wp = &Wt[(t * 16 + m16) * 136 + quad * 8];
#pragma unroll
        for (int kk = 0; kk < 4; ++kk) {
            half8 b = *(const half8*)(wp + kk * 32);
            acc[t] = __builtin_amdgcn_mfma_f32_16x16x32_f16(a[kk], b, acc[t], 0, 0, 0);
        }
    }
    float dis[4];
#pragma unroll
    for (int r = 0; r < 4; ++r) {
        int row = row0 + quad * 4 + r;
        dis[r] = (row < N_NODES) ? rsqrtf(1.0f + (float)ideg[row]) : 0.f;
    }
#pragma unroll
    for (int t = 0; t < 2; ++t) {
        int c = t * 16 + m16;
#pragma unroll
        for (int r = 0; r < 4; ++r) {
            int row = row0 + quad * 4 + r;
            if (row < N_NODES)
                T[(size_t)row * IN_F + c] = (_Float16)(acc[t][r] * dis[r]);
        }
    }
}

// ---------------- launch ----------------

extern "C" void kernel_launch(void* const* d_in, const int* in_sizes, int n_in,
                              void* d_out, int out_size, void* d_ws, size_t ws_size,
                              hipStream_t stream) {
    const float* x  = (const float*)d_in[0];
    const int*   ei = (const int*)d_in[1];
    const float* W1 = (const float*)d_in[2];
    const float* b1 = (const float*)d_in[3];
    const float* W2 = (const float*)d_in[4];
    const float* b2 = (const float*)d_in[5];
    const float* W3 = (const float*)d_in[6];
    const float* b3 = (const float*)d_in[7];
    float* out = (float*)d_out;

    const int* src = ei;             // edge_index[0]
    const int* dst = ei + N_EDGES;   // edge_index[1]

    // workspace layout
    int*      ideg     = (int*)d_ws;                           // N (padded 102400)
    int*      cursor   = ideg + 102400;                        // N
    int*      partials = cursor + 102400;                      // 512
    int*      col      = partials + 512;                       // E
    __half2*  t1h      = (__half2*)(col + N_EDGES);            // N*16 half2 (L1 msgs)
    float*    z        = (float*)(t1h + (size_t)N_NODES * 16); // N*32 fp32
    _Float16* H1h      = (_Float16*)(z + (size_t)N_NODES * IN_F);   // N*128 fp16
    _Float16* T2h      = H1h + (size_t)N_NODES * HID;          // N*128 fp16 (reused as T3)
    _Float16* H2h      = T2h + (size_t)N_NODES * HID;          // N*128 fp16

    const int xgrid = (N_NODES + 63) / 64;   // 1563

    // ---- CSR build ----
    k_zero_ideg<<<NBLK_SCAN, 256, 0, stream>>>(ideg);
    k_count<<<(N_EDGES + 255) / 256, 256, 0, stream>>>(dst, ideg);
    k_scan1<<<NBLK_SCAN, 256, 0, stream>>>(ideg, cursor, partials);
    k_scan2<<<1, 512, 0, stream>>>(partials);
    k_scan3<<<NBLK_SCAN, 256, 0, stream>>>(cursor, partials);
    k_fill<<<(N_EDGES + 255) / 256, 256, 0, stream>>>(src, dst, cursor, col);

    // ---- layer 1 (aggregate-first; 32-dim gather, then MFMA 32->128) ----
    k_prescale<<<(N_NODES * 16 + 255) / 256, 256, 0, stream>>>(
        (const float2*)x, ideg, t1h);
    k_gather32h_pre<<<(N_NODES + 15) / 16, 256, 0, stream>>>(
        cursor, ideg, col, t1h, (float2*)z);
    k_xform1_mfma<<<xgrid, 256, 0, stream>>>(z, W1, b1, H1h);

    // ---- layer 2 (MFMA 128->128, then 128-dim fp16 gather) ----
    k_xform2_mfma<<<xgrid, 256, 0, stream>>>(H1h, W2, ideg, T2h);
    k_gather128h<<<(N_NODES + 3) / 4, 256, 0, stream>>>(
        cursor, ideg, col, (const __half2*)T2h, b2, (__half2*)H2h);

    // ---- layer 3 (MFMA 128->32, then 32-dim fp16 gather) ----
    k_xform3_mfma<<<xgrid, 256, 0, stream>>>(H2h, W3, ideg, T2h);
    k_gather32h_fin<<<(N_NODES + 15) / 16, 256, 0, stream>>>(
        cursor, ideg, col, (const __half2*)T2h, b3, (float2*)out);
}

// Round 6
// 390.593 us; speedup vs baseline: 4.6991x; 1.1632x over previous
//
#include <hip/hip_runtime.h>
#include <hip/hip_fp16.h>

#define N_NODES 100000
#define N_EDGES 1600000
#define IN_F 32
#define HID 128
#define NBLK_SCAN 391   // ceil(100000/256)
#define BSHIFT 9
#define BSIZE 512
#define NBUCK 196       // ceil(100000/512)
#define EPB 2048        // edges per k_bucket block
#define NBB 782         // ceil(E/EPB)

typedef _Float16 half8 __attribute__((ext_vector_type(8)));
typedef float floatx4 __attribute__((ext_vector_type(4)));

static __device__ __forceinline__ void pack2(_Float16* dst, float a, float b) {
    union { _Float16 h[2]; unsigned u; } p;
    p.h[0] = (_Float16)a; p.h[1] = (_Float16)b;
    *(unsigned*)dst = p.u;
}

// ---------------- CSR build ----------------

__global__ void k_zero_ideg(int* __restrict__ ideg) {
    int i = blockIdx.x * 256 + threadIdx.x;
    if (i < N_NODES) ideg[i] = 0;
}

__global__ void k_count(const int* __restrict__ dst, int* __restrict__ ideg) {
    int e = blockIdx.x * 256 + threadIdx.x;
    if (e < N_EDGES) atomicAdd(&ideg[dst[e]], 1);
}

__global__ __launch_bounds__(256) void k_scan1(const int* __restrict__ ideg,
                                               int* __restrict__ cursor,
                                               int* __restrict__ partials) {
    __shared__ int s[256];
    int gid = blockIdx.x * 256 + threadIdx.x;
    int v = (gid < N_NODES) ? ideg[gid] : 0;
    s[threadIdx.x] = v;
    __syncthreads();
    for (int off = 1; off < 256; off <<= 1) {
        int t = (threadIdx.x >= off) ? s[threadIdx.x - off] : 0;
        __syncthreads();
        s[threadIdx.x] += t;
        __syncthreads();
    }
    if (gid < N_NODES) cursor[gid] = s[threadIdx.x] - v;   // exclusive
    if (threadIdx.x == 255) partials[blockIdx.x] = s[255];
}

__global__ __launch_bounds__(512) void k_scan2(int* __restrict__ partials) {
    __shared__ int s[512];
    int v = (threadIdx.x < NBLK_SCAN) ? partials[threadIdx.x] : 0;
    s[threadIdx.x] = v;
    __syncthreads();
    for (int off = 1; off < 512; off <<= 1) {
        int t = (threadIdx.x >= off) ? s[threadIdx.x - off] : 0;
        __syncthreads();
        s[threadIdx.x] += t;
        __syncthreads();
    }
    if (threadIdx.x < NBLK_SCAN) partials[threadIdx.x] = s[threadIdx.x] - v;
}

__global__ void k_scan3(int* __restrict__ cursor, const int* __restrict__ partials) {
    int gid = blockIdx.x * 256 + threadIdx.x;
    if (gid < N_NODES) cursor[gid] += partials[blockIdx.x];
}

// bucket write-cursors: bcur[b] = cursor[b*512] (bucket regions are node-aligned col slices)
__global__ void k_binit(const int* __restrict__ cursor, int* __restrict__ bcur) {
    int t = threadIdx.x;
    if (t < NBUCK) bcur[t] = cursor[t << BSHIFT];
}

// phase 1: bucket-scatter packed recs (src<<9 | dst_local), contiguous runs per bucket
__global__ __launch_bounds__(256) void k_bucket(const int* __restrict__ src,
                                                const int* __restrict__ dst,
                                                int* __restrict__ bcur,
                                                unsigned* __restrict__ rec) {
    __shared__ int hist[256];
    __shared__ int lbase[256];
    const int e0 = blockIdx.x * EPB;
    hist[threadIdx.x] = 0;
    __syncthreads();

    unsigned rk[8]; int bk[8];
#pragma unroll
    for (int k = 0; k < 8; ++k) {
        int e = e0 + k * 256 + threadIdx.x;
        if (e < N_EDGES) {
            int d = dst[e];
            int b = d >> BSHIFT;
            bk[k] = b;
            rk[k] = ((unsigned)src[e] << BSHIFT) | (unsigned)(d & (BSIZE - 1));
            atomicAdd(&hist[b], 1);
        } else bk[k] = -1;
    }
    __syncthreads();
    int c = hist[threadIdx.x];
    lbase[threadIdx.x] = (c > 0) ? atomicAdd(&bcur[threadIdx.x], c) : 0;
    __syncthreads();
    hist[threadIdx.x] = 0;   // reuse as local running offset
    __syncthreads();
#pragma unroll
    for (int k = 0; k < 8; ++k) {
        if (bk[k] >= 0) {
            int off = atomicAdd(&hist[bk[k]], 1);
            rec[lbase[bk[k]] + off] = rk[k];
        }
    }
}

// phase 2: one block per bucket; LDS per-node cursors (exclusive), L2-local col writes
__global__ __launch_bounds__(256) void k_fill2(const int* __restrict__ cursor,
                                               const unsigned* __restrict__ rec,
                                               int* __restrict__ col) {
    __shared__ int lcur[BSIZE];
    const int b = blockIdx.x;
    const int n0 = b << BSHIFT;
    for (int t = threadIdx.x; t < BSIZE; t += 256) {
        int n = n0 + t;
        lcur[t] = (n < N_NODES) ? cursor[n] : 0;
    }
    const int rbeg = cursor[n0];
    const int rend = (b == NBUCK - 1) ? N_EDGES : cursor[n0 + BSIZE];
    __syncthreads();
    for (int i = rbeg + threadIdx.x; i < rend; i += 256) {
        unsigned r = rec[i];
        int slot = atomicAdd(&lcur[r & (BSIZE - 1)], 1);
        col[slot] = (int)(r >> BSHIFT);
    }
}

// ---------------- layer-1 prescale: t1 = x * dis (fp16, 32-dim) ----------------

__global__ void k_prescale(const float2* __restrict__ x, const int* __restrict__ ideg,
                           __half2* __restrict__ T) {
    int tid = blockIdx.x * 256 + threadIdx.x;   // N*16 half2 elements
    if (tid >= N_NODES * 16) return;
    int i = tid >> 4;
    float dis = rsqrtf(1.0f + (float)ideg[i]);
    float2 v = x[tid];
    T[tid] = __floats2half2_rn(v.x * dis, v.y * dis);
}

// ---------------- gathers (CSR, fp16 messages, half2 lanes) ----------------

__global__ __launch_bounds__(256) void k_gather32h_pre(
    const int* __restrict__ cursor, const int* __restrict__ ideg,
    const int* __restrict__ col, const __half2* __restrict__ T,
    float2* __restrict__ OUT) {
    int node = blockIdx.x * 16 + (threadIdx.x >> 4);
    int j = threadIdx.x & 15;
    if (node >= N_NODES) return;
    int e   = cursor[node];
    int d   = ideg[node];
    int end = e + d;
    float2 acc = __half22float2(T[(size_t)node * 16 + j]);   // self-loop
    for (; e + 3 < end; e += 4) {
        int s0 = col[e], s1 = col[e + 1], s2 = col[e + 2], s3 = col[e + 3];
        float2 f0 = __half22float2(T[(size_t)s0 * 16 + j]);
        float2 f1 = __half22float2(T[(size_t)s1 * 16 + j]);
        float2 f2 = __half22float2(T[(size_t)s2 * 16 + j]);
        float2 f3 = __half22float2(T[(size_t)s3 * 16 + j]);
        acc.x += (f0.x + f1.x) + (f2.x + f3.x);
        acc.y += (f0.y + f1.y) + (f2.y + f3.y);
    }
    for (; e < end; ++e) {
        float2 f = __half22float2(T[(size_t)col[e] * 16 + j]);
        acc.x += f.x; acc.y += f.y;
    }
    float dis = rsqrtf(1.0f + (float)d);
    OUT[(size_t)node * 16 + j] = make_float2(acc.x * dis, acc.y * dis);
}

__global__ __launch_bounds__(256) void k_gather32h_fin(
    const int* __restrict__ cursor, const int* __restrict__ ideg,
    const int* __restrict__ col, const __half2* __restrict__ T,
    const float* __restrict__ b, float2* __restrict__ OUT) {
    int node = blockIdx.x * 16 + (threadIdx.x >> 4);
    int j = threadIdx.x & 15;
    if (node >= N_NODES) return;
    int e   = cursor[node];
    int d   = ideg[node];
    int end = e + d;
    float2 acc = __half22float2(T[(size_t)node * 16 + j]);   // self-loop
    for (; e + 3 < end; e += 4) {
        int s0 = col[e], s1 = col[e + 1], s2 = col[e + 2], s3 = col[e + 3];
        float2 f0 = __half22float2(T[(size_t)s0 * 16 + j]);
        float2 f1 = __half22float2(T[(size_t)s1 * 16 + j]);
        float2 f2 = __half22float2(T[(size_t)s2 * 16 + j]);
        float2 f3 = __half22float2(T[(size_t)s3 * 16 + j]);
        acc.x += (f0.x + f1.x) + (f2.x + f3.x);
        acc.y += (f0.y + f1.y) + (f2.y + f3.y);
    }
    for (; e < end; ++e) {
        float2 f = __half22float2(T[(size_t)col[e] * 16 + j]);
        acc.x += f.x; acc.y += f.y;
    }
    float dis = rsqrtf(1.0f + (float)d);
    float vx = acc.x * dis + b[2 * j];
    float vy = acc.y * dis + b[2 * j + 1];
    OUT[(size_t)node * 16 + j] =
        make_float2(vx > 0.f ? vx : 0.f, vy > 0.f ? vy : 0.f);
}

__global__ __launch_bounds__(256) void k_gather128h(
    const int* __restrict__ cursor, const int* __restrict__ ideg,
    const int* __restrict__ col, const __half2* __restrict__ T,
    const float* __restrict__ b, __half2* __restrict__ OUT) {
    int node = blockIdx.x * 4 + (threadIdx.x >> 6);
    int j = threadIdx.x & 63;
    if (node >= N_NODES) return;
    int e   = cursor[node];
    int d   = ideg[node];
    int end = e + d;
    float2 acc = __half22float2(T[(size_t)node * 64 + j]);   // self-loop
    for (; e + 3 < end; e += 4) {
        int s0 = col[e], s1 = col[e + 1], s2 = col[e + 2], s3 = col[e + 3];
        float2 f0 = __half22float2(T[(size_t)s0 * 64 + j]);
        float2 f1 = __half22float2(T[(size_t)s1 * 64 + j]);
        float2 f2 = __half22float2(T[(size_t)s2 * 64 + j]);
        float2 f3 = __half22float2(T[(size_t)s3 * 64 + j]);
        acc.x += (f0.x + f1.x) + (f2.x + f3.x);
        acc.y += (f0.y + f1.y) + (f2.y + f3.y);
    }
    for (; e < end; ++e) {
        float2 f = __half22float2(T[(size_t)col[e] * 64 + j]);
        acc.x += f.x; acc.y += f.y;
    }
    float dis = rsqrtf(1.0f + (float)d);
    float vx = acc.x * dis + b[2 * j];
    float vy = acc.y * dis + b[2 * j + 1];
    OUT[(size_t)node * 64 + j] =
        __floats2half2_rn(vx > 0.f ? vx : 0.f, vy > 0.f ? vy : 0.f);
}

// ---------------- MFMA transforms ----------------
// 16x16x32 layouts: A[m=lane&15][k=quad*8+j], B[k=quad*8+j][n=lane&15],
// D[row=quad*4+r][col=lane&15]. Block = 4 waves x 16 rows = 64 rows.

__global__ __launch_bounds__(256) void k_xform1_mfma(
    const float* __restrict__ z, const float* __restrict__ W,
    const float* __restrict__ bias, _Float16* __restrict__ Hh) {
    __shared__ _Float16 Wt[128 * 40];
    for (int idx = threadIdx.x; idx < 2048; idx += 256) {
        int n = idx & 127, k = (idx >> 7) * 2;
        pack2(&Wt[n * 40 + k], W[k * HID + n], W[(k + 1) * HID + n]);
    }
    __syncthreads();

    const int lane = threadIdx.x & 63;
    const int wave = threadIdx.x >> 6;
    const int m16 = lane & 15, quad = lane >> 4;
    const int row0 = blockIdx.x * 64 + wave * 16;
    if (row0 >= N_NODES) return;

    int arow = row0 + m16; if (arow >= N_NODES) arow = N_NODES - 1;
    const float* zp = z + (size_t)arow * IN_F + quad * 8;
    float4 z0 = *(const float4*)zp;
    float4 z1 = *(const float4*)(zp + 4);
    half8 a = {(_Float16)z0.x, (_Float16)z0.y, (_Float16)z0.z, (_Float16)z0.w,
               (_Float16)z1.x, (_Float16)z1.y, (_Float16)z1.z, (_Float16)z1.w};

    floatx4 acc[8];
#pragma unroll
    for (int t = 0; t < 8; ++t) acc[t] = (floatx4){0.f, 0.f, 0.f, 0.f};
#pragma unroll
    for (int t = 0; t < 8; ++t) {
        half8 b = *(const half8*)&Wt[(t * 16 + m16) * 40 + quad * 8];
        acc[t] = __builtin_amdgcn_mfma_f32_16x16x32_f16(a, b, acc[t], 0, 0, 0);
    }
#pragma unroll
    for (int t = 0; t < 8; ++t) {
        int c = t * 16 + m16;
        float bj = bias[c];
#pragma unroll
        for (int r = 0; r < 4; ++r) {
            int row = row0 + quad * 4 + r;
            if (row < N_NODES) {
                float v = acc[t][r] + bj;
                Hh[(size_t)row * HID + c] = (_Float16)(v > 0.f ? v : 0.f);
            }
        }
    }
}

__global__ __launch_bounds__(256) void k_xform2_mfma(
    const _Float16* __restrict__ H, const float* __restrict__ W,
    const int* __restrict__ ideg, _Float16* __restrict__ T) {
    __shared__ _Float16 Wt[128 * 136];
    for (int idx = threadIdx.x; idx < 8192; idx += 256) {
        int n = idx & 127, k = (idx >> 7) * 2;
        pack2(&Wt[n * 136 + k], W[k * HID + n], W[(k + 1) * HID + n]);
    }
    __syncthreads();

    const int lane = threadIdx.x & 63;
    const int wave = threadIdx.x >> 6;
    const int m16 = lane & 15, quad = lane >> 4;
    const int row0 = blockIdx.x * 64 + wave * 16;
    if (row0 >= N_NODES) return;

    int arow = row0 + m16; if (arow >= N_NODES) arow = N_NODES - 1;
    const _Float16* hp = H + (size_t)arow * HID + quad * 8;
    half8 a[4];
#pragma unroll
    for (int kk = 0; kk < 4; ++kk) a[kk] = *(const half8*)(hp + kk * 32);

    floatx4 acc[8];
#pragma unroll
    for (int t = 0; t < 8; ++t) acc[t] = (floatx4){0.f, 0.f, 0.f, 0.f};
#pragma unroll
    for (int t = 0; t < 8; ++t) {
        const _Float16* wp = &Wt[(t * 16 + m16) * 136 + quad * 8];
#pragma unroll
        for (int kk = 0; kk < 4; ++kk) {
            half8 b = *(const half8*)(wp + kk * 32);
            acc[t] = __builtin_amdgcn_mfma_f32_16x16x32_f16(a[kk], b, acc[t], 0, 0, 0);
        }
    }
    float dis[4];
#pragma unroll
    for (int r = 0; r < 4; ++r) {
        int row = row0 + quad * 4 + r;
        dis[r] = (row < N_NODES) ? rsqrtf(1.0f + (float)ideg[row]) : 0.f;
    }
#pragma unroll
    for (int t = 0; t < 8; ++t) {
        int c = t * 16 + m16;
#pragma unroll
        for (int r = 0; r < 4; ++r) {
            int row = row0 + quad * 4 + r;
            if (row < N_NODES)
                T[(size_t)row * HID + c] = (_Float16)(acc[t][r] * dis[r]);
        }
    }
}

__global__ __launch_bounds__(256) void k_xform3_mfma(
    const _Float16* __restrict__ H, const float* __restrict__ W,
    const int* __restrict__ ideg, _Float16* __restrict__ T) {
    __shared__ _Float16 Wt[32 * 136];
    for (int idx = threadIdx.x; idx < 2048; idx += 256) {
        int n = idx & 31, k = (idx >> 5) * 2;
        pack2(&Wt[n * 136 + k], W[k * IN_F + n], W[(k + 1) * IN_F + n]);
    }
    __syncthreads();

    const int lane = threadIdx.x & 63;
    const int wave = threadIdx.x >> 6;
    const int m16 = lane & 15, quad = lane >> 4;
    const int row0 = blockIdx.x * 64 + wave * 16;
    if (row0 >= N_NODES) return;

    int arow = row0 + m16; if (arow >= N_NODES) arow = N_NODES - 1;
    const _Float16* hp = H + (size_t)arow * HID + quad * 8;
    half8 a[4];
#pragma unroll
    for (int kk = 0; kk < 4; ++kk) a[kk] = *(const half8*)(hp + kk * 32);

    floatx4 acc[2];
#pragma unroll
    for (int t = 0; t < 2; ++t) acc[t] = (floatx4){0.f, 0.f, 0.f, 0.f};
#pragma unroll
    for (int t = 0; t < 2; ++t) {
        const _Float16* wp = &Wt[(t * 16 + m16) * 136 + quad * 8];
#pragma unroll
        for (int kk = 0; kk < 4; ++kk) {
            half8 b = *(const half8*)(wp + kk * 32);
            acc[t] = __builtin_amdgcn_mfma_f32_16x16x32_f16(a[kk], b, acc[t], 0, 0, 0);
        }
    }
    float dis[4];
#pragma unroll
    for (int r = 0; r < 4; ++r) {
        int row = row0 + quad * 4 + r;
        dis[r] = (row < N_NODES) ? rsqrtf(1.0f + (float)ideg[row]) : 0.f;
    }
#pragma unroll
    for (int t = 0; t < 2; ++t) {
        int c = t * 16 + m16;
#pragma unroll
        for (int r = 0; r < 4; ++r) {
            int row = row0 + quad * 4 + r;
            if (row < N_NODES)
                T[(size_t)row * IN_F + c] = (_Float16)(acc[t][r] * dis[r]);
        }
    }
}

// ---------------- launch ----------------

extern "C" void kernel_launch(void* const* d_in, const int* in_sizes, int n_in,
                              void* d_out, int out_size, void* d_ws, size_t ws_size,
                              hipStream_t stream) {
    const float* x  = (const float*)d_in[0];
    const int*   ei = (const int*)d_in[1];
    const float* W1 = (const float*)d_in[2];
    const float* b1 = (const float*)d_in[3];
    const float* W2 = (const float*)d_in[4];
    const float* b2 = (const float*)d_in[5];
    const float* W3 = (const float*)d_in[6];
    const float* b3 = (const float*)d_in[7];
    float* out = (float*)d_out;

    const int* src = ei;             // edge_index[0]
    const int* dst = ei + N_EDGES;   // edge_index[1]

    // workspace layout
    int*      ideg     = (int*)d_ws;                           // N (padded 102400)
    int*      cursor   = ideg + 102400;                        // N
    int*      partials = cursor + 102400;                      // 512
    int*      bcur     = partials + 512;                       // 256
    int*      col      = bcur + 256;                           // E
    unsigned* rec      = (unsigned*)(col + N_EDGES);           // E
    __half2*  t1h      = (__half2*)(rec + N_EDGES);            // N*16 half2 (L1 msgs)
    float*    z        = (float*)(t1h + (size_t)N_NODES * 16); // N*32 fp32
    _Float16* H1h      = (_Float16*)(z + (size_t)N_NODES * IN_F);   // N*128 fp16
    _Float16* T2h      = H1h + (size_t)N_NODES * HID;          // N*128 fp16 (reused as T3)
    _Float16* H2h      = T2h + (size_t)N_NODES * HID;          // N*128 fp16

    const int xgrid = (N_NODES + 63) / 64;   // 1563

    // ---- CSR build ----
    k_zero_ideg<<<NBLK_SCAN, 256, 0, stream>>>(ideg);
    k_count<<<(N_EDGES + 255) / 256, 256, 0, stream>>>(dst, ideg);
    k_scan1<<<NBLK_SCAN, 256, 0, stream>>>(ideg, cursor, partials);
    k_scan2<<<1, 512, 0, stream>>>(partials);
    k_scan3<<<NBLK_SCAN, 256, 0, stream>>>(cursor, partials);
    k_binit<<<1, 256, 0, stream>>>(cursor, bcur);
    k_bucket<<<NBB, 256, 0, stream>>>(src, dst, bcur, rec);
    k_fill2<<<NBUCK, 256, 0, stream>>>(cursor, rec, col);

    // ---- layer 1 (aggregate-first; 32-dim gather, then MFMA 32->128) ----
    k_prescale<<<(N_NODES * 16 + 255) / 256, 256, 0, stream>>>(
        (const float2*)x, ideg, t1h);
    k_gather32h_pre<<<(N_NODES + 15) / 16, 256, 0, stream>>>(
        cursor, ideg, col, t1h, (float2*)z);
    k_xform1_mfma<<<xgrid, 256, 0, stream>>>(z, W1, b1, H1h);

    // ---- layer 2 (MFMA 128->128, then 128-dim fp16 gather) ----
    k_xform2_mfma<<<xgrid, 256, 0, stream>>>(H1h, W2, ideg, T2h);
    k_gather128h<<<(N_NODES + 3) / 4, 256, 0, stream>>>(
        cursor, ideg, col, (const __half2*)T2h, b2, (__half2*)H2h);

    // ---- layer 3 (MFMA 128->32, then 32-dim fp16 gather) ----
    k_xform3_mfma<<<xgrid, 256, 0, stream>>>(H2h, W3, ideg, T2h);
    k_gather32h_fin<<<(N_NODES + 15) / 16, 256, 0, stream>>>(
        cursor, ideg, col, (const __half2*)T2h, b3, (float2*)out);
}

// Round 7
// 386.059 us; speedup vs baseline: 4.7543x; 1.0117x over previous
//
#include <hip/hip_runtime.h>
#include <hip/hip_fp16.h>

#define N_NODES 100000
#define N_EDGES 1600000
#define IN_F 32
#define HID 128
#define NBLK_SCAN 391   // ceil(100000/256)
#define BSHIFT 9
#define BSIZE 512
#define NBUCK 196       // ceil(100000/512)
#define EPB 8192        // edges per k_bucket block
#define NBB 196         // ceil(E/EPB) = 1600000/8192 = 195.3 -> 196

typedef _Float16 half8 __attribute__((ext_vector_type(8)));
typedef float floatx4 __attribute__((ext_vector_type(4)));

static __device__ __forceinline__ void pack2(_Float16* dst, float a, float b) {
    union { _Float16 h[2]; unsigned u; } p;
    p.h[0] = (_Float16)a; p.h[1] = (_Float16)b;
    *(unsigned*)dst = p.u;
}

// ---------------- CSR build ----------------

__global__ void k_zero_ideg(int* __restrict__ ideg) {
    int i = blockIdx.x * 256 + threadIdx.x;
    if (i < N_NODES) ideg[i] = 0;
}

__global__ void k_count(const int* __restrict__ dst, int* __restrict__ ideg) {
    int e = blockIdx.x * 256 + threadIdx.x;
    if (e < N_EDGES) atomicAdd(&ideg[dst[e]], 1);
}

__global__ __launch_bounds__(256) void k_scan1(const int* __restrict__ ideg,
                                               int* __restrict__ cursor,
                                               int* __restrict__ partials) {
    __shared__ int s[256];
    int gid = blockIdx.x * 256 + threadIdx.x;
    int v = (gid < N_NODES) ? ideg[gid] : 0;
    s[threadIdx.x] = v;
    __syncthreads();
    for (int off = 1; off < 256; off <<= 1) {
        int t = (threadIdx.x >= off) ? s[threadIdx.x - off] : 0;
        __syncthreads();
        s[threadIdx.x] += t;
        __syncthreads();
    }
    if (gid < N_NODES) cursor[gid] = s[threadIdx.x] - v;   // exclusive
    if (threadIdx.x == 255) partials[blockIdx.x] = s[255];
}

__global__ __launch_bounds__(512) void k_scan2(int* __restrict__ partials) {
    __shared__ int s[512];
    int v = (threadIdx.x < NBLK_SCAN) ? partials[threadIdx.x] : 0;
    s[threadIdx.x] = v;
    __syncthreads();
    for (int off = 1; off < 512; off <<= 1) {
        int t = (threadIdx.x >= off) ? s[threadIdx.x - off] : 0;
        __syncthreads();
        s[threadIdx.x] += t;
        __syncthreads();
    }
    if (threadIdx.x < NBLK_SCAN) partials[threadIdx.x] = s[threadIdx.x] - v;
}

__global__ void k_scan3(int* __restrict__ cursor, const int* __restrict__ partials) {
    int gid = blockIdx.x * 256 + threadIdx.x;
    if (gid < N_NODES) cursor[gid] += partials[blockIdx.x];
}

__global__ void k_binit(const int* __restrict__ cursor, int* __restrict__ bcur) {
    int t = threadIdx.x;
    if (t < NBUCK) bcur[t] = cursor[t << BSHIFT];
}

// phase 1: bucket-scatter packed recs (src<<9 | dst_local), contiguous runs per bucket
__global__ __launch_bounds__(256) void k_bucket(const int* __restrict__ src,
                                                const int* __restrict__ dst,
                                                int* __restrict__ bcur,
                                                unsigned* __restrict__ rec) {
    __shared__ int hist[256];
    __shared__ int lbase[256];
    const int e0 = blockIdx.x * EPB;
    hist[threadIdx.x] = 0;
    __syncthreads();

    unsigned rk[32]; short bk[32];
#pragma unroll
    for (int k = 0; k < 32; ++k) {
        int e = e0 + k * 256 + threadIdx.x;
        if (e < N_EDGES) {
            int d = dst[e];
            int b = d >> BSHIFT;
            bk[k] = (short)b;
            rk[k] = ((unsigned)src[e] << BSHIFT) | (unsigned)(d & (BSIZE - 1));
            atomicAdd(&hist[b], 1);
        } else bk[k] = -1;
    }
    __syncthreads();
    int c = hist[threadIdx.x];
    lbase[threadIdx.x] = (c > 0) ? atomicAdd(&bcur[threadIdx.x], c) : 0;
    __syncthreads();
    hist[threadIdx.x] = 0;   // reuse as local running offset
    __syncthreads();
#pragma unroll
    for (int k = 0; k < 32; ++k) {
        if (bk[k] >= 0) {
            int off = atomicAdd(&hist[bk[k]], 1);
            rec[lbase[bk[k]] + off] = rk[k];
        }
    }
}

// phase 2: one block per bucket; LDS per-node cursors, L2-local col writes
__global__ __launch_bounds__(256) void k_fill2(const int* __restrict__ cursor,
                                               const unsigned* __restrict__ rec,
                                               int* __restrict__ col) {
    __shared__ int lcur[BSIZE];
    const int b = blockIdx.x;
    const int n0 = b << BSHIFT;
    for (int t = threadIdx.x; t < BSIZE; t += 256) {
        int n = n0 + t;
        lcur[t] = (n < N_NODES) ? cursor[n] : 0;
    }
    const int rbeg = cursor[n0];
    const int rend = (b == NBUCK - 1) ? N_EDGES : cursor[n0 + BSIZE];
    __syncthreads();
    for (int i = rbeg + threadIdx.x; i < rend; i += 256) {
        unsigned r = rec[i];
        int slot = atomicAdd(&lcur[r & (BSIZE - 1)], 1);
        col[slot] = (int)(r >> BSHIFT);
    }
}

// ---------------- layer-1 prescale: t1 = x * dis (fp16, 32-dim) ----------------

__global__ void k_prescale(const float2* __restrict__ x, const int* __restrict__ ideg,
                           __half2* __restrict__ T) {
    int tid = blockIdx.x * 256 + threadIdx.x;   // N*16 half2 elements
    if (tid >= N_NODES * 16) return;
    int i = tid >> 4;
    float dis = rsqrtf(1.0f + (float)ideg[i]);
    float2 v = x[tid];
    T[tid] = __floats2half2_rn(v.x * dis, v.y * dis);
}

// ---------------- gathers v2: node-per-wave, (edge-slot, feat-block) lanes ----------------
// 32-dim: 16 slots x 4 feat-lanes (half8 each). Persistent grid-stride waves.

// pre: z = acc*dis, fp16 out
__global__ __launch_bounds__(256) void k_gather32_pre(
    const int* __restrict__ cursor, const int* __restrict__ ideg,
    const int* __restrict__ col, const _Float16* __restrict__ T,
    _Float16* __restrict__ OUT) {
    const int lane = threadIdx.x & 63;
    const int slot = lane >> 2;          // 0..15
    const int fl   = lane & 3;           // feats [fl*8, fl*8+8)
    const int wid  = blockIdx.x * 4 + (threadIdx.x >> 6);
    const int wstride = gridDim.x * 4;

    for (int node = wid; node < N_NODES; node += wstride) {
        int begin = cursor[node];
        int d     = ideg[node];
        int end   = begin + d;
        float acc[8];
        if (slot == 0) {
            half8 v = *(const half8*)(T + (size_t)node * IN_F + fl * 8);
#pragma unroll
            for (int i = 0; i < 8; ++i) acc[i] = (float)v[i];
        } else {
#pragma unroll
            for (int i = 0; i < 8; ++i) acc[i] = 0.f;
        }
        for (int e = begin; e < end; e += 16) {
            int ee = e + slot;
            if (ee < end) {
                int s = col[ee];
                half8 v = *(const half8*)(T + (size_t)s * IN_F + fl * 8);
#pragma unroll
                for (int i = 0; i < 8; ++i) acc[i] += (float)v[i];
            }
        }
#pragma unroll
        for (int m = 4; m < 64; m <<= 1)
#pragma unroll
            for (int i = 0; i < 8; ++i) acc[i] += __shfl_xor(acc[i], m, 64);
        if (slot == 0) {
            float dis = rsqrtf(1.0f + (float)d);
            half8 o;
#pragma unroll
            for (int i = 0; i < 8; ++i) o[i] = (_Float16)(acc[i] * dis);
            *(half8*)(OUT + (size_t)node * IN_F + fl * 8) = o;
        }
    }
}

// fin: out = relu(acc*dis + b), fp32 out
__global__ __launch_bounds__(256) void k_gather32_fin(
    const int* __restrict__ cursor, const int* __restrict__ ideg,
    const int* __restrict__ col, const _Float16* __restrict__ T,
    const float* __restrict__ b, float* __restrict__ OUT) {
    const int lane = threadIdx.x & 63;
    const int slot = lane >> 2;
    const int fl   = lane & 3;
    const int wid  = blockIdx.x * 4 + (threadIdx.x >> 6);
    const int wstride = gridDim.x * 4;

    float4 bb0 = *(const float4*)(b + fl * 8);
    float4 bb1 = *(const float4*)(b + fl * 8 + 4);
    float bias[8] = {bb0.x, bb0.y, bb0.z, bb0.w, bb1.x, bb1.y, bb1.z, bb1.w};

    for (int node = wid; node < N_NODES; node += wstride) {
        int begin = cursor[node];
        int d     = ideg[node];
        int end   = begin + d;
        float acc[8];
        if (slot == 0) {
            half8 v = *(const half8*)(T + (size_t)node * IN_F + fl * 8);
#pragma unroll
            for (int i = 0; i < 8; ++i) acc[i] = (float)v[i];
        } else {
#pragma unroll
            for (int i = 0; i < 8; ++i) acc[i] = 0.f;
        }
        for (int e = begin; e < end; e += 16) {
            int ee = e + slot;
            if (ee < end) {
                int s = col[ee];
                half8 v = *(const half8*)(T + (size_t)s * IN_F + fl * 8);
#pragma unroll
                for (int i = 0; i < 8; ++i) acc[i] += (float)v[i];
            }
        }
#pragma unroll
        for (int m = 4; m < 64; m <<= 1)
#pragma unroll
            for (int i = 0; i < 8; ++i) acc[i] += __shfl_xor(acc[i], m, 64);
        if (slot == 0) {
            float dis = rsqrtf(1.0f + (float)d);
            float o[8];
#pragma unroll
            for (int i = 0; i < 8; ++i) {
                float v = acc[i] * dis + bias[i];
                o[i] = v > 0.f ? v : 0.f;
            }
            float* op = OUT + (size_t)node * IN_F + fl * 8;
            *(float4*)op       = make_float4(o[0], o[1], o[2], o[3]);
            *(float4*)(op + 4) = make_float4(o[4], o[5], o[6], o[7]);
        }
    }
}

// 128-dim: 4 slots x 16 feat-lanes (half8 each), x2 unroll; fp16 out = relu(acc*dis+b)
__global__ __launch_bounds__(256) void k_gather128(
    const int* __restrict__ cursor, const int* __restrict__ ideg,
    const int* __restrict__ col, const _Float16* __restrict__ T,
    const float* __restrict__ b, _Float16* __restrict__ OUT) {
    const int lane = threadIdx.x & 63;
    const int slot = lane >> 4;          // 0..3
    const int fl   = lane & 15;          // feats [fl*8, fl*8+8)
    const int wid  = blockIdx.x * 4 + (threadIdx.x >> 6);
    const int wstride = gridDim.x * 4;

    float4 bb0 = *(const float4*)(b + fl * 8);
    float4 bb1 = *(const float4*)(b + fl * 8 + 4);
    float bias[8] = {bb0.x, bb0.y, bb0.z, bb0.w, bb1.x, bb1.y, bb1.z, bb1.w};

    for (int node = wid; node < N_NODES; node += wstride) {
        int begin = cursor[node];
        int d     = ideg[node];
        int end   = begin + d;
        float acc[8];
        if (slot == 0) {
            half8 v = *(const half8*)(T + (size_t)node * HID + fl * 8);
#pragma unroll
            for (int i = 0; i < 8; ++i) acc[i] = (float)v[i];
        } else {
#pragma unroll
            for (int i = 0; i < 8; ++i) acc[i] = 0.f;
        }
        for (int e = begin; e < end; e += 8) {
            int ee0 = e + slot;
            int ee1 = e + 4 + slot;
            if (ee1 < end) {            // both active (common path)
                int s0 = col[ee0];
                int s1 = col[ee1];
                half8 v0 = *(const half8*)(T + (size_t)s0 * HID + fl * 8);
                half8 v1 = *(const half8*)(T + (size_t)s1 * HID + fl * 8);
#pragma unroll
                for (int i = 0; i < 8; ++i) acc[i] += (float)v0[i] + (float)v1[i];
            } else if (ee0 < end) {
                int s0 = col[ee0];
                half8 v0 = *(const half8*)(T + (size_t)s0 * HID + fl * 8);
#pragma unroll
                for (int i = 0; i < 8; ++i) acc[i] += (float)v0[i];
            }
        }
#pragma unroll
        for (int m = 16; m < 64; m <<= 1)
#pragma unroll
            for (int i = 0; i < 8; ++i) acc[i] += __shfl_xor(acc[i], m, 64);
        if (slot == 0) {
            float dis = rsqrtf(1.0f + (float)d);
            half8 o;
#pragma unroll
            for (int i = 0; i < 8; ++i) {
                float v = acc[i] * dis + bias[i];
                o[i] = (_Float16)(v > 0.f ? v : 0.f);
            }
            *(half8*)(OUT + (size_t)node * HID + fl * 8) = o;
        }
    }
}

// ---------------- MFMA transforms ----------------
// 16x16x32 layouts: A[m=lane&15][k=quad*8+j], B[k=quad*8+j][n=lane&15],
// D[row=quad*4+r][col=lane&15]. Block = 4 waves x 16 rows = 64 rows.

// layer 1: H1 = relu(z @ W1 + b1); z fp16 [N,32], H1 fp16 [N,128]
__global__ __launch_bounds__(256) void k_xform1_mfma(
    const _Float16* __restrict__ z, const float* __restrict__ W,
    const float* __restrict__ bias, _Float16* __restrict__ Hh) {
    __shared__ _Float16 Wt[128 * 40];
    for (int idx = threadIdx.x; idx < 2048; idx += 256) {
        int n = idx & 127, k = (idx >> 7) * 2;
        pack2(&Wt[n * 40 + k], W[k * HID + n], W[(k + 1) * HID + n]);
    }
    __syncthreads();

    const int lane = threadIdx.x & 63;
    const int wave = threadIdx.x >> 6;
    const int m16 = lane & 15, quad = lane >> 4;
    const int row0 = blockIdx.x * 64 + wave * 16;
    if (row0 >= N_NODES) return;

    int arow = row0 + m16; if (arow >= N_NODES) arow = N_NODES - 1;
    half8 a = *(const half8*)(z + (size_t)arow * IN_F + quad * 8);

    floatx4 acc[8];
#pragma unroll
    for (int t = 0; t < 8; ++t) acc[t] = (floatx4){0.f, 0.f, 0.f, 0.f};
#pragma unroll
    for (int t = 0; t < 8; ++t) {
        half8 b = *(const half8*)&Wt[(t * 16 + m16) * 40 + quad * 8];
        acc[t] = __builtin_amdgcn_mfma_f32_16x16x32_f16(a, b, acc[t], 0, 0, 0);
    }
#pragma unroll
    for (int t = 0; t < 8; ++t) {
        int c = t * 16 + m16;
        float bj = bias[c];
#pragma unroll
        for (int r = 0; r < 4; ++r) {
            int row = row0 + quad * 4 + r;
            if (row < N_NODES) {
                float v = acc[t][r] + bj;
                Hh[(size_t)row * HID + c] = (_Float16)(v > 0.f ? v : 0.f);
            }
        }
    }
}

__global__ __launch_bounds__(256) void k_xform2_mfma(
    const _Float16* __restrict__ H, const float* __restrict__ W,
    const int* __restrict__ ideg, _Float16* __restrict__ T) {
    __shared__ _Float16 Wt[128 * 136];
    for (int idx = threadIdx.x; idx < 8192; idx += 256) {
        int n = idx & 127, k = (idx >> 7) * 2;
        pack2(&Wt[n * 136 + k], W[k * HID + n], W[(k + 1) * HID + n]);
    }
    __syncthreads();

    const int lane = threadIdx.x & 63;
    const int wave = threadIdx.x >> 6;
    const int m16 = lane & 15, quad = lane >> 4;
    const int row0 = blockIdx.x * 64 + wave * 16;
    if (row0 >= N_NODES) return;

    int arow = row0 + m16; if (arow >= N_NODES) arow = N_NODES - 1;
    const _Float16* hp = H + (size_t)arow * HID + quad * 8;
    half8 a[4];
#pragma unroll
    for (int kk = 0; kk < 4; ++kk) a[kk] = *(const half8*)(hp + kk * 32);

    floatx4 acc[8];
#pragma unroll
    for (int t = 0; t < 8; ++t) acc[t] = (floatx4){0.f, 0.f, 0.f, 0.f};
#pragma unroll
    for (int t = 0; t < 8; ++t) {
        const _Float16* wp = &Wt[(t * 16 + m16) * 136 + quad * 8];
#pragma unroll
        for (int kk = 0; kk < 4; ++kk) {
            half8 b = *(const half8*)(wp + kk * 32);
            acc[t] = __builtin_amdgcn_mfma_f32_16x16x32_f16(a[kk], b, acc[t], 0, 0, 0);
        }
    }
    float dis[4];
#pragma unroll
    for (int r = 0; r < 4; ++r) {
        int row = row0 + quad * 4 + r;
        dis[r] = (row < N_NODES) ? rsqrtf(1.0f + (float)ideg[row]) : 0.f;
    }
#pragma unroll
    for (int t = 0; t < 8; ++t) {
        int c = t * 16 + m16;
#pragma unroll
        for (int r = 0; r < 4; ++r) {
            int row = row0 + quad * 4 + r;
            if (row < N_NODES)
                T[(size_t)row * HID + c] = (_Float16)(acc[t][r] * dis[r]);
        }
    }
}

__global__ __launch_bounds__(256) void k_xform3_mfma(
    const _Float16* __restrict__ H, const float* __restrict__ W,
    const int* __restrict__ ideg, _Float16* __restrict__ T) {
    __shared__ _Float16 Wt[32 * 136];
    for (int idx = threadIdx.x; idx < 2048; idx += 256) {
        int n = idx & 31, k = (idx >> 5) * 2;
        pack2(&Wt[n * 136 + k], W[k * IN_F + n], W[(k + 1) * IN_F + n]);
    }
    __syncthreads();

    const int lane = threadIdx.x & 63;
    const int wave = threadIdx.x >> 6;
    const int m16 = lane & 15, quad = lane >> 4;
    const int row0 = blockIdx.x * 64 + wave * 16;
    if (row0 >= N_NODES) return;

    int arow = row0 + m16; if (arow >= N_NODES) arow = N_NODES - 1;
    const _Float16* hp = H + (size_t)arow * HID + quad * 8;
    half8 a[4];
#pragma unroll
    for (int kk = 0; kk < 4; ++kk) a[kk] = *(const half8*)(hp + kk * 32);

    floatx4 acc[2];
#pragma unroll
    for (int t = 0; t < 2; ++t) acc[t] = (floatx4){0.f, 0.f, 0.f, 0.f};
#pragma unroll
    for (int t = 0; t < 2; ++t) {
        const _Float16* wp = &Wt[(t * 16 + m16) * 136 + quad * 8];
#pragma unroll
        for (int kk = 0; kk < 4; ++kk) {
            half8 b = *(const half8*)(wp + kk * 32);
            acc[t] = __builtin_amdgcn_mfma_f32_16x16x32_f16(a[kk], b, acc[t], 0, 0, 0);
        }
    }
    float dis[4];
#pragma unroll
    for (int r = 0; r < 4; ++r) {
        int row = row0 + quad * 4 + r;
        dis[r] = (row < N_NODES) ? rsqrtf(1.0f + (float)ideg[row]) : 0.f;
    }
#pragma unroll
    for (int t = 0; t < 2; ++t) {
        int c = t * 16 + m16;
#pragma unroll
        for (int r = 0; r < 4; ++r) {
            int row = row0 + quad * 4 + r;
            if (row < N_NODES)
                T[(size_t)row * IN_F + c] = (_Float16)(acc[t][r] * dis[r]);
        }
    }
}

// ---------------- launch ----------------

extern "C" void kernel_launch(void* const* d_in, const int* in_sizes, int n_in,
                              void* d_out, int out_size, void* d_ws, size_t ws_size,
                              hipStream_t stream) {
    const float* x  = (const float*)d_in[0];
    const int*   ei = (const int*)d_in[1];
    const float* W1 = (const float*)d_in[2];
    const float* b1 = (const float*)d_in[3];
    const float* W2 = (const float*)d_in[4];
    const float* b2 = (const float*)d_in[5];
    const float* W3 = (const float*)d_in[6];
    const float* b3 = (const float*)d_in[7];
    float* out = (float*)d_out;

    const int* src = ei;             // edge_index[0]
    const int* dst = ei + N_EDGES;   // edge_index[1]

    // workspace layout (all offsets 16B-aligned)
    int*      ideg     = (int*)d_ws;                           // N (padded 102400)
    int*      cursor   = ideg + 102400;                        // N
    int*      partials = cursor + 102400;                      // 512
    int*      bcur     = partials + 512;                       // 256
    int*      col      = bcur + 256;                           // E
    unsigned* rec      = (unsigned*)(col + N_EDGES);           // E
    _Float16* t1h      = (_Float16*)(rec + N_EDGES);           // N*32 fp16 (L1 msgs)
    _Float16* z        = t1h + (size_t)N_NODES * IN_F;         // N*32 fp16
    _Float16* H1h      = z + (size_t)N_NODES * IN_F;           // N*128 fp16
    _Float16* T2h      = H1h + (size_t)N_NODES * HID;          // N*128 fp16 (reused as T3)
    _Float16* H2h      = T2h + (size_t)N_NODES * HID;          // N*128 fp16

    const int xgrid = (N_NODES + 63) / 64;   // 1563

    // ---- CSR build ----
    k_zero_ideg<<<NBLK_SCAN, 256, 0, stream>>>(ideg);
    k_count<<<(N_EDGES + 255) / 256, 256, 0, stream>>>(dst, ideg);
    k_scan1<<<NBLK_SCAN, 256, 0, stream>>>(ideg, cursor, partials);
    k_scan2<<<1, 512, 0, stream>>>(partials);
    k_scan3<<<NBLK_SCAN, 256, 0, stream>>>(cursor, partials);
    k_binit<<<1, 256, 0, stream>>>(cursor, bcur);
    k_bucket<<<NBB, 256, 0, stream>>>(src, dst, bcur, rec);
    k_fill2<<<NBUCK, 256, 0, stream>>>(cursor, rec, col);

    // ---- layer 1 (aggregate-first; 32-dim gather, then MFMA 32->128) ----
    k_prescale<<<(N_NODES * 16 + 255) / 256, 256, 0, stream>>>(
        (const float2*)x, ideg, (__half2*)t1h);
    k_gather32_pre<<<2048, 256, 0, stream>>>(cursor, ideg, col, t1h, z);
    k_xform1_mfma<<<xgrid, 256, 0, stream>>>(z, W1, b1, H1h);

    // ---- layer 2 (MFMA 128->128, then 128-dim fp16 gather) ----
    k_xform2_mfma<<<xgrid, 256, 0, stream>>>(H1h, W2, ideg, T2h);
    k_gather128<<<2048, 256, 0, stream>>>(cursor, ideg, col, T2h, b2, H2h);

    // ---- layer 3 (MFMA 128->32, then 32-dim fp16 gather) ----
    k_xform3_mfma<<<xgrid, 256, 0, stream>>>(H2h, W3, ideg, T2h);
    k_gather32_fin<<<2048, 256, 0, stream>>>(cursor, ideg, col, T2h, b3, out);
}

// Round 9
// 332.888 us; speedup vs baseline: 5.5136x; 1.1597x over previous
//
#include <hip/hip_runtime.h>
#include <hip/hip_fp16.h>

#define N_NODES 100000
#define N_EDGES 1600000
#define IN_F 32
#define HID 128
#define BSHIFT 9
#define BSIZE 512
#define NBUCK 196       // ceil(100000/512)
#define EPB 8192        // edges per bucket-phase block
#define NBB 196         // ceil(E/EPB)

typedef _Float16 half8 __attribute__((ext_vector_type(8)));
typedef float floatx4 __attribute__((ext_vector_type(4)));

static __device__ __forceinline__ void pack2(_Float16* dst, float a, float b) {
    union { _Float16 h[2]; unsigned u; } p;
    p.h[0] = (_Float16)a; p.h[1] = (_Float16)b;
    *(unsigned*)dst = p.u;
}

// ---------------- CSR build (bucketed, no global per-node atomics) ----------------

__global__ void k_zero_bcnt(int* __restrict__ bcnt) {
    if (threadIdx.x < 256) bcnt[threadIdx.x] = 0;
}

// per-bucket totals: LDS histogram, one global atomic per (block,bucket)
__global__ __launch_bounds__(256) void k_bcount(const int* __restrict__ dst,
                                                int* __restrict__ bcnt) {
    __shared__ int hist[256];
    hist[threadIdx.x] = 0;
    __syncthreads();
    const int e0 = blockIdx.x * EPB;
#pragma unroll 4
    for (int k = 0; k < 32; ++k) {
        int e = e0 + k * 256 + threadIdx.x;
        if (e < N_EDGES) atomicAdd(&hist[dst[e] >> BSHIFT], 1);
    }
    __syncthreads();
    int c = hist[threadIdx.x];
    if (c > 0) atomicAdd(&bcnt[threadIdx.x], c);
}

// single-block scan of bucket totals -> bbase[NBUCK+1], bcur init
__global__ __launch_bounds__(256) void k_bscan(const int* __restrict__ bcnt,
                                               int* __restrict__ bbase,
                                               int* __restrict__ bcur) {
    __shared__ int s[256];
    int v = (threadIdx.x < NBUCK) ? bcnt[threadIdx.x] : 0;
    s[threadIdx.x] = v;
    __syncthreads();
    for (int off = 1; off < 256; off <<= 1) {
        int t = (threadIdx.x >= off) ? s[threadIdx.x - off] : 0;
        __syncthreads();
        s[threadIdx.x] += t;
        __syncthreads();
    }
    if (threadIdx.x < NBUCK) {
        int ex = s[threadIdx.x] - v;
        bbase[threadIdx.x] = ex;
        bcur[threadIdx.x]  = ex;
    }
    if (threadIdx.x == 0) bbase[NBUCK] = N_EDGES;
}

// scatter packed recs (src<<9 | dst_local) into contiguous bucket runs
__global__ __launch_bounds__(256) void k_bucket(const int* __restrict__ src,
                                                const int* __restrict__ dst,
                                                int* __restrict__ bcur,
                                                unsigned* __restrict__ rec) {
    __shared__ int hist[256];
    __shared__ int lbase[256];
    const int e0 = blockIdx.x * EPB;
    hist[threadIdx.x] = 0;
    __syncthreads();

    unsigned rk[32]; short bk[32];
#pragma unroll
    for (int k = 0; k < 32; ++k) {
        int e = e0 + k * 256 + threadIdx.x;
        if (e < N_EDGES) {
            int d = dst[e];
            int b = d >> BSHIFT;
            bk[k] = (short)b;
            rk[k] = ((unsigned)src[e] << BSHIFT) | (unsigned)(d & (BSIZE - 1));
            atomicAdd(&hist[b], 1);
        } else bk[k] = -1;
    }
    __syncthreads();
    int c = hist[threadIdx.x];
    lbase[threadIdx.x] = (c > 0) ? atomicAdd(&bcur[threadIdx.x], c) : 0;
    __syncthreads();
    hist[threadIdx.x] = 0;   // reuse as local running offset
    __syncthreads();
#pragma unroll
    for (int k = 0; k < 32; ++k) {
        if (bk[k] >= 0) {
            int off = atomicAdd(&hist[bk[k]], 1);
            rec[lbase[bk[k]] + off] = rk[k];
        }
    }
}

// per bucket: LDS degree count + LDS scan -> ideg/cursor (coalesced) + col scatter
__global__ __launch_bounds__(256) void k_fill3(const unsigned* __restrict__ rec,
                                               const int* __restrict__ bbase,
                                               int* __restrict__ ideg,
                                               int* __restrict__ cursor,
                                               int* __restrict__ col) {
    __shared__ int lcnt[BSIZE];
    __shared__ int lcur[BSIZE];
    __shared__ int s[256];
    const int b = blockIdx.x;
    const int n0 = b << BSHIFT;
    const int rbeg = bbase[b];
    const int rend = bbase[b + 1];

    lcnt[threadIdx.x] = 0;
    lcnt[threadIdx.x + 256] = 0;
    __syncthreads();
    for (int i = rbeg + threadIdx.x; i < rend; i += 256)
        atomicAdd(&lcnt[rec[i] & (BSIZE - 1)], 1);
    __syncthreads();

    // exclusive scan of 512 counts with 256 threads (pair + Hillis-Steele)
    int a0 = lcnt[2 * threadIdx.x], a1 = lcnt[2 * threadIdx.x + 1];
    int pv = a0 + a1;
    s[threadIdx.x] = pv;
    __syncthreads();
    for (int off = 1; off < 256; off <<= 1) {
        int t = (threadIdx.x >= off) ? s[threadIdx.x - off] : 0;
        __syncthreads();
        s[threadIdx.x] += t;
        __syncthreads();
    }
    int ex = s[threadIdx.x] - pv;            // exclusive over pairs
    lcur[2 * threadIdx.x]     = rbeg + ex;
    lcur[2 * threadIdx.x + 1] = rbeg + ex + a0;
    __syncthreads();

    // coalesced per-node outputs
    for (int t = threadIdx.x; t < BSIZE; t += 256) {
        int n = n0 + t;
        if (n < N_NODES) {
            ideg[n]   = lcnt[t];
            cursor[n] = lcur[t];
        }
    }
    __syncthreads();
    // col scatter via LDS cursors (L2-local: bucket slice of col)
    for (int i = rbeg + threadIdx.x; i < rend; i += 256) {
        unsigned r = rec[i];
        int slot = atomicAdd(&lcur[r & (BSIZE - 1)], 1);
        col[slot] = (int)(r >> BSHIFT);
    }
}

// ---------------- layer-1 prescale: t1 = x * dis (fp16, 32-dim) ----------------

__global__ void k_prescale(const float2* __restrict__ x, const int* __restrict__ ideg,
                           __half2* __restrict__ T) {
    int tid = blockIdx.x * 256 + threadIdx.x;   // N*16 half2 elements
    if (tid >= N_NODES * 16) return;
    int i = tid >> 4;
    float dis = rsqrtf(1.0f + (float)ideg[i]);
    float2 v = x[tid];
    T[tid] = __floats2half2_rn(v.x * dis, v.y * dis);
}

// ---------------- gathers: node-per-wave, (edge-slot, feat-block) lanes ----------------

// pre: z = acc*dis, fp16 out. 16 slots x 4 feat-lanes.
__global__ __launch_bounds__(256) void k_gather32_pre(
    const int* __restrict__ cursor, const int* __restrict__ ideg,
    const int* __restrict__ col, const _Float16* __restrict__ T,
    _Float16* __restrict__ OUT) {
    const int lane = threadIdx.x & 63;
    const int slot = lane >> 2;
    const int fl   = lane & 3;
    const int wid  = blockIdx.x * 4 + (threadIdx.x >> 6);
    const int wstride = gridDim.x * 4;

    for (int node = wid; node < N_NODES; node += wstride) {
        int begin = cursor[node];
        int d     = ideg[node];
        int end   = begin + d;
        float acc[8];
        if (slot == 0) {
            half8 v = *(const half8*)(T + (size_t)node * IN_F + fl * 8);
#pragma unroll
            for (int i = 0; i < 8; ++i) acc[i] = (float)v[i];
        } else {
#pragma unroll
            for (int i = 0; i < 8; ++i) acc[i] = 0.f;
        }
        for (int e = begin; e < end; e += 16) {
            int ee = e + slot;
            if (ee < end) {
                int s = col[ee];
                half8 v = *(const half8*)(T + (size_t)s * IN_F + fl * 8);
#pragma unroll
                for (int i = 0; i < 8; ++i) acc[i] += (float)v[i];
            }
        }
#pragma unroll
        for (int m = 4; m < 64; m <<= 1)
#pragma unroll
            for (int i = 0; i < 8; ++i) acc[i] += __shfl_xor(acc[i], m, 64);
        if (slot == 0) {
            float dis = rsqrtf(1.0f + (float)d);
            half8 o;
#pragma unroll
            for (int i = 0; i < 8; ++i) o[i] = (_Float16)(acc[i] * dis);
            *(half8*)(OUT + (size_t)node * IN_F + fl * 8) = o;
        }
    }
}

// fin: out = relu(acc*dis + b), fp32 out
__global__ __launch_bounds__(256) void k_gather32_fin(
    const int* __restrict__ cursor, const int* __restrict__ ideg,
    const int* __restrict__ col, const _Float16* __restrict__ T,
    const float* __restrict__ b, float* __restrict__ OUT) {
    const int lane = threadIdx.x & 63;
    const int slot = lane >> 2;
    const int fl   = lane & 3;
    const int wid  = blockIdx.x * 4 + (threadIdx.x >> 6);
    const int wstride = gridDim.x * 4;

    float4 bb0 = *(const float4*)(b + fl * 8);
    float4 bb1 = *(const float4*)(b + fl * 8 + 4);
    float bias[8] = {bb0.x, bb0.y, bb0.z, bb0.w, bb1.x, bb1.y, bb1.z, bb1.w};

    for (int node = wid; node < N_NODES; node += wstride) {
        int begin = cursor[node];
        int d     = ideg[node];
        int end   = begin + d;
        float acc[8];
        if (slot == 0) {
            half8 v = *(const half8*)(T + (size_t)node * IN_F + fl * 8);
#pragma unroll
            for (int i = 0; i < 8; ++i) acc[i] = (float)v[i];
        } else {
#pragma unroll
            for (int i = 0; i < 8; ++i) acc[i] = 0.f;
        }
        for (int e = begin; e < end; e += 16) {
            int ee = e + slot;
            if (ee < end) {
                int s = col[ee];
                half8 v = *(const half8*)(T + (size_t)s * IN_F + fl * 8);
#pragma unroll
                for (int i = 0; i < 8; ++i) acc[i] += (float)v[i];
            }
        }
#pragma unroll
        for (int m = 4; m < 64; m <<= 1)
#pragma unroll
            for (int i = 0; i < 8; ++i) acc[i] += __shfl_xor(acc[i], m, 64);
        if (slot == 0) {
            float dis = rsqrtf(1.0f + (float)d);
            float o[8];
#pragma unroll
            for (int i = 0; i < 8; ++i) {
                float v = acc[i] * dis + bias[i];
                o[i] = v > 0.f ? v : 0.f;
            }
            float* op = OUT + (size_t)node * IN_F + fl * 8;
            *(float4*)op       = make_float4(o[0], o[1], o[2], o[3]);
            *(float4*)(op + 4) = make_float4(o[4], o[5], o[6], o[7]);
        }
    }
}

// 128-dim: 4 slots x 16 feat-lanes, x2 unroll; fp16 out = relu(acc*dis+b)
__global__ __launch_bounds__(256) void k_gather128(
    const int* __restrict__ cursor, const int* __restrict__ ideg,
    const int* __restrict__ col, const _Float16* __restrict__ T,
    const float* __restrict__ b, _Float16* __restrict__ OUT) {
    const int lane = threadIdx.x & 63;
    const int slot = lane >> 4;
    const int fl   = lane & 15;
    const int wid  = blockIdx.x * 4 + (threadIdx.x >> 6);
    const int wstride = gridDim.x * 4;

    float4 bb0 = *(const float4*)(b + fl * 8);
    float4 bb1 = *(const float4*)(b + fl * 8 + 4);
    float bias[8] = {bb0.x, bb0.y, bb0.z, bb0.w, bb1.x, bb1.y, bb1.z, bb1.w};

    for (int node = wid; node < N_NODES; node += wstride) {
        int begin = cursor[node];
        int d     = ideg[node];
        int end   = begin + d;
        float acc[8];
        if (slot == 0) {
            half8 v = *(const half8*)(T + (size_t)node * HID + fl * 8);
#pragma unroll
            for (int i = 0; i < 8; ++i) acc[i] = (float)v[i];
        } else {
#pragma unroll
            for (int i = 0; i < 8; ++i) acc[i] = 0.f;
        }
        for (int e = begin; e < end; e += 8) {
            int ee0 = e + slot;
            int ee1 = e + 4 + slot;
            if (ee1 < end) {
                int s0 = col[ee0];
                int s1 = col[ee1];
                half8 v0 = *(const half8*)(T + (size_t)s0 * HID + fl * 8);
                half8 v1 = *(const half8*)(T + (size_t)s1 * HID + fl * 8);
#pragma unroll
                for (int i = 0; i < 8; ++i) acc[i] += (float)v0[i] + (float)v1[i];
            } else if (ee0 < end) {
                int s0 = col[ee0];
                half8 v0 = *(const half8*)(T + (size_t)s0 * HID + fl * 8);
#pragma unroll
                for (int i = 0; i < 8; ++i) acc[i] += (float)v0[i];
            }
        }
#pragma unroll
        for (int m = 16; m < 64; m <<= 1)
#pragma unroll
            for (int i = 0; i < 8; ++i) acc[i] += __shfl_xor(acc[i], m, 64);
        if (slot == 0) {
            float dis = rsqrtf(1.0f + (float)d);
            half8 o;
#pragma unroll
            for (int i = 0; i < 8; ++i) {
                float v = acc[i] * dis + bias[i];
                o[i] = (_Float16)(v > 0.f ? v : 0.f);
            }
            *(half8*)(OUT + (size_t)node * HID + fl * 8) = o;
        }
    }
}

// ---------------- MFMA transforms ----------------
// 16x16x32 layouts: A[m=lane&15][k=quad*8+j], B[k=quad*8+j][n=lane&15],
// D[row=quad*4+r][col=lane&15]. Block = 4 waves x 16 rows = 64 rows.

__global__ __launch_bounds__(256) void k_xform1_mfma(
    const _Float16* __restrict__ z, const float* __restrict__ W,
    const float* __restrict__ bias, _Float16* __restrict__ Hh) {
    __shared__ _Float16 Wt[128 * 40];
    for (int idx = threadIdx.x; idx < 2048; idx += 256) {
        int n = idx & 127, k = (idx >> 7) * 2;
        pack2(&Wt[n * 40 + k], W[k * HID + n], W[(k + 1) * HID + n]);
    }
    __syncthreads();

    const int lane = threadIdx.x & 63;
    const int wave = threadIdx.x >> 6;
    const int m16 = lane & 15, quad = lane >> 4;
    const int row0 = blockIdx.x * 64 + wave * 16;
    if (row0 >= N_NODES) return;

    int arow = row0 + m16; if (arow >= N_NODES) arow = N_NODES - 1;
    half8 a = *(const half8*)(z + (size_t)arow * IN_F + quad * 8);

    floatx4 acc[8];
#pragma unroll
    for (int t = 0; t < 8; ++t) acc[t] = (floatx4){0.f, 0.f, 0.f, 0.f};
#pragma unroll
    for (int t = 0; t < 8; ++t) {
        half8 b = *(const half8*)&Wt[(t * 16 + m16) * 40 + quad * 8];
        acc[t] = __builtin_amdgcn_mfma_f32_16x16x32_f16(a, b, acc[t], 0, 0, 0);
    }
#pragma unroll
    for (int t = 0; t < 8; ++t) {
        int c = t * 16 + m16;
        float bj = bias[c];
#pragma unroll
        for (int r = 0; r < 4; ++r) {
            int row = row0 + quad * 4 + r;
            if (row < N_NODES) {
                float v = acc[t][r] + bj;
                Hh[(size_t)row * HID + c] = (_Float16)(v > 0.f ? v : 0.f);
            }
        }
    }
}

__global__ __launch_bounds__(256) void k_xform2_mfma(
    const _Float16* __restrict__ H, const float* __restrict__ W,
    const int* __restrict__ ideg, _Float16* __restrict__ T) {
    __shared__ _Float16 Wt[128 * 136];
    for (int idx = threadIdx.x; idx < 8192; idx += 256) {
        int n = idx & 127, k = (idx >> 7) * 2;
        pack2(&Wt[n * 136 + k], W[k * HID + n], W[(k + 1) * HID + n]);
    }
    __syncthreads();

    const int lane = threadIdx.x & 63;
    const int wave = threadIdx.x >> 6;
    const int m16 = lane & 15, quad = lane >> 4;
    const int row0 = blockIdx.x * 64 + wave * 16;
    if (row0 >= N_NODES) return;

    int arow = row0 + m16; if (arow >= N_NODES) arow = N_NODES - 1;
    const _Float16* hp = H + (size_t)arow * HID + quad * 8;
    half8 a[4];
#pragma unroll
    for (int kk = 0; kk < 4; ++kk) a[kk] = *(const half8*)(hp + kk * 32);

    floatx4 acc[8];
#pragma unroll
    for (int t = 0; t < 8; ++t) acc[t] = (floatx4){0.f, 0.f, 0.f, 0.f};
#pragma unroll
    for (int t = 0; t < 8; ++t) {
        const _Float16* wp = &Wt[(t * 16 + m16) * 136 + quad * 8];
#pragma unroll
        for (int kk = 0; kk < 4; ++kk) {
            half8 b = *(const half8*)(wp + kk * 32);
            acc[t] = __builtin_amdgcn_mfma_f32_16x16x32_f16(a[kk], b, acc[t], 0, 0, 0);
        }
    }
    float dis[4];
#pragma unroll
    for (int r = 0; r < 4; ++r) {
        int row = row0 + quad * 4 + r;
        dis[r] = (row < N_NODES) ? rsqrtf(1.0f + (float)ideg[row]) : 0.f;
    }
#pragma unroll
    for (int t = 0; t < 8; ++t) {
        int c = t * 16 + m16;
#pragma unroll
        for (int r = 0; r < 4; ++r) {
            int row = row0 + quad * 4 + r;
            if (row < N_NODES)
                T[(size_t)row * HID + c] = (_Float16)(acc[t][r] * dis[r]);
        }
    }
}

__global__ __launch_bounds__(256) void k_xform3_mfma(
    const _Float16* __restrict__ H, const float* __restrict__ W,
    const int* __restrict__ ideg, _Float16* __restrict__ T) {
    __shared__ _Float16 Wt[32 * 136];
    for (int idx = threadIdx.x; idx < 2048; idx += 256) {
        int n = idx & 31, k = (idx >> 5) * 2;
        pack2(&Wt[n * 136 + k], W[k * IN_F + n], W[(k + 1) * IN_F + n]);
    }
    __syncthreads();

    const int lane = threadIdx.x & 63;
    const int wave = threadIdx.x >> 6;
    const int m16 = lane & 15, quad = lane >> 4;
    const int row0 = blockIdx.x * 64 + wave * 16;
    if (row0 >= N_NODES) return;

    int arow = row0 + m16; if (arow >= N_NODES) arow = N_NODES - 1;
    const _Float16* hp = H + (size_t)arow * HID + quad * 8;
    half8 a[4];
#pragma unroll
    for (int kk = 0; kk < 4; ++kk) a[kk] = *(const half8*)(hp + kk * 32);

    floatx4 acc[2];
#pragma unroll
    for (int t = 0; t < 2; ++t) acc[t] = (floatx4){0.f, 0.f, 0.f, 0.f};
#pragma unroll
    for (int t = 0; t < 2; ++t) {
        const _Float16* wp = &Wt[(t * 16 + m16) * 136 + quad * 8];
#pragma unroll
        for (int kk = 0; kk < 4; ++kk) {
            half8 b = *(const half8*)(wp + kk * 32);
            acc[t] = __builtin_amdgcn_mfma_f32_16x16x32_f16(a[kk], b, acc[t], 0, 0, 0);
        }
    }
    float dis[4];
#pragma unroll
    for (int r = 0; r < 4; ++r) {
        int row = row0 + quad * 4 + r;
        dis[r] = (row < N_NODES) ? rsqrtf(1.0f + (float)ideg[row]) : 0.f;
    }
#pragma unroll
    for (int t = 0; t < 2; ++t) {
        int c = t * 16 + m16;
#pragma unroll
        for (int r = 0; r < 4; ++r) {
            int row = row0 + quad * 4 + r;
            if (row < N_NODES)
                T[(size_t)row * IN_F + c] = (_Float16)(acc[t][r] * dis[r]);
        }
    }
}

// ---------------- launch ----------------

extern "C" void kernel_launch(void* const* d_in, const int* in_sizes, int n_in,
                              void* d_out, int out_size, void* d_ws, size_t ws_size,
                              hipStream_t stream) {
    const float* x  = (const float*)d_in[0];
    const int*   ei = (const int*)d_in[1];
    const float* W1 = (const float*)d_in[2];
    const float* b1 = (const float*)d_in[3];
    const float* W2 = (const float*)d_in[4];
    const float* b2 = (const float*)d_in[5];
    const float* W3 = (const float*)d_in[6];
    const float* b3 = (const float*)d_in[7];
    float* out = (float*)d_out;

    const int* src = ei;             // edge_index[0]
    const int* dst = ei + N_EDGES;   // edge_index[1]

    // workspace layout (all offsets 16B-aligned)
    int*      ideg   = (int*)d_ws;                           // N (padded 102400)
    int*      cursor = ideg + 102400;                        // N
    int*      bcnt   = cursor + 102400;                      // 256
    int*      bbase  = bcnt + 256;                           // 256 (197 used)
    int*      bcur   = bbase + 256;                          // 256
    int*      col    = bcur + 256;                           // E
    unsigned* rec    = (unsigned*)(col + N_EDGES);           // E
    _Float16* t1h    = (_Float16*)(rec + N_EDGES);           // N*32 fp16 (L1 msgs)
    _Float16* z      = t1h + (size_t)N_NODES * IN_F;         // N*32 fp16
    _Float16* H1h    = z + (size_t)N_NODES * IN_F;           // N*128 fp16
    _Float16* T2h    = H1h + (size_t)N_NODES * HID;          // N*128 fp16 (reused as T3)
    _Float16* H2h    = T2h + (size_t)N_NODES * HID;          // N*128 fp16

    const int xgrid = (N_NODES + 63) / 64;   // 1563

    // ---- CSR build (bucketed; no global per-node atomics) ----
    k_zero_bcnt<<<1, 256, 0, stream>>>(bcnt);
    k_bcount<<<NBB, 256, 0, stream>>>(dst, bcnt);
    k_bscan<<<1, 256, 0, stream>>>(bcnt, bbase, bcur);
    k_bucket<<<NBB, 256, 0, stream>>>(src, dst, bcur, rec);
    k_fill3<<<NBUCK, 256, 0, stream>>>(rec, bbase, ideg, cursor, col);

    // ---- layer 1 (aggregate-first; 32-dim gather, then MFMA 32->128) ----
    k_prescale<<<(N_NODES * 16 + 255) / 256, 256, 0, stream>>>(
        (const float2*)x, ideg, (__half2*)t1h);
    k_gather32_pre<<<2048, 256, 0, stream>>>(cursor, ideg, col, t1h, z);
    k_xform1_mfma<<<xgrid, 256, 0, stream>>>(z, W1, b1, H1h);

    // ---- layer 2 (MFMA 128->128, then 128-dim fp16 gather) ----
    k_xform2_mfma<<<xgrid, 256, 0, stream>>>(H1h, W2, ideg, T2h);
    k_gather128<<<2048, 256, 0, stream>>>(cursor, ideg, col, T2h, b2, H2h);

    // ---- layer 3 (MFMA 128->32, then 32-dim fp16 gather) ----
    k_xform3_mfma<<<xgrid, 256, 0, stream>>>(H2h, W3, ideg, T2h);
    k_gather32_fin<<<2048, 256, 0, stream>>>(cursor, ideg, col, T2h, b3, out);
}